// Round 2
// baseline (514.625 us; speedup 1.0000x reference)
//
#include <hip/hip_runtime.h>
#include <hip/hip_bf16.h>
#include <cstdint>
#include <cstddef>

typedef unsigned short u16;
typedef __bf16 bf16x8 __attribute__((ext_vector_type(8)));
typedef __bf16 bf16x4 __attribute__((ext_vector_type(4)));
typedef short   s16x4 __attribute__((ext_vector_type(4)));
typedef float    f32x4 __attribute__((ext_vector_type(4)));
typedef unsigned short u16x2 __attribute__((ext_vector_type(2)));
typedef unsigned short u16x4 __attribute__((ext_vector_type(4)));
typedef unsigned short u16x8 __attribute__((ext_vector_type(8)));

#define DEVI static __device__ __forceinline__

DEVI float b2f(u16 u){ union{unsigned i; float v;} x; x.i=((unsigned)u)<<16; return x.v; }
DEVI u16 f2b(float f){ union{float v; unsigned i;} x; x.v=f; unsigned r=x.i+0x7FFFu+((x.i>>16)&1u); return (u16)(r>>16); }
DEVI f32x4 mfma16(bf16x8 a, bf16x8 b, f32x4 c){ return __builtin_amdgcn_mfma_f32_16x16x32_bf16(a,b,c,0,0,0); }
DEVI f32x4 mfma16k16(bf16x4 a, bf16x4 b, f32x4 c){
#if __has_builtin(__builtin_amdgcn_mfma_f32_16x16x16_bf16)
  return __builtin_amdgcn_mfma_f32_16x16x16_bf16(a,b,c,0,0,0);
#elif __has_builtin(__builtin_amdgcn_mfma_f32_16x16x16bf16_1k)
  return __builtin_amdgcn_mfma_f32_16x16x16bf16_1k((s16x4)a,(s16x4)b,c,0,0,0);
#else
  asm volatile("v_mfma_f32_16x16x16_bf16 %0, %1, %2, %0" : "+v"(c) : "v"(a), "v"(b));
  return c;
#endif
}
DEVI void gload16(const void* g, void* l){
  __builtin_amdgcn_global_load_lds((const __attribute__((address_space(1))) void*)g,
                                   (__attribute__((address_space(3))) void*)l, 16, 0, 0);
}
DEVI float silu_f(float x){ return x/(1.f+__expf(-x)); }

// ---------------- workspace layout (bytes) ----------------
static constexpr size_t OFF_WC   = 0;
static constexpr size_t OFF_WQKV = OFF_WC   + (size_t)1024*1024*2;
static constexpr size_t OFF_WPROJ= OFF_WQKV + (size_t)3072*1024*2;
static constexpr size_t OFF_WEXP = OFF_WPROJ+ (size_t)1024*1024*2;
static constexpr size_t OFF_WW12 = OFF_WEXP + (size_t)1024*1024*2;
static constexpr size_t OFF_WW3  = OFF_WW12 + (size_t)5504*1024*2;
static constexpr size_t OFF_ADA  = OFF_WW3  + (size_t)1024*2752*2;
static constexpr size_t OFF_X2   = OFF_ADA  + (size_t)4*6144*4;
static constexpr size_t OFF_P1   = OFF_X2   + (size_t)4096*1024*4;
static constexpr size_t OFF_H1   = OFF_P1;
static constexpr size_t OFF_HC   = OFF_H1   + (size_t)4096*1024*2;
static constexpr size_t OFF_QKVO = OFF_HC   + (size_t)4096*1024*2;
static constexpr size_t OFF_X12  = OFF_P1;                       // reuse: h1/hc/qkvO dead
static constexpr size_t OFF_P2   = OFF_P1   + (size_t)4096*5504*2;
static constexpr size_t OFF_Q    = OFF_P2;
static constexpr size_t OFF_K    = OFF_Q    + (size_t)64*1024*64*2;
static constexpr size_t OFF_VT   = OFF_K    + (size_t)64*1024*64*2;
static constexpr size_t OFF_O    = OFF_VT   + (size_t)64*1024*64*2;
static constexpr size_t OFF_PR   = OFF_O    + (size_t)4096*1024*2;
static constexpr size_t OFF_H2   = OFF_PR   + (size_t)4096*1024*2;
static constexpr size_t OFF_HID  = OFF_P2;                       // reuse: q/k/vt dead

// ---------------- fp32 -> bf16 weight conversion with zero padding ----------------
__global__ __launch_bounds__(256) void convert_pad(const float* __restrict__ src, u16* __restrict__ dst,
                                                   int R, int C, int Cpad)
{
  int r = blockIdx.y;
  int c0 = (blockIdx.x*256 + threadIdx.x)*4;
  if (c0 >= Cpad) return;
  u16x4 o;
#pragma unroll
  for (int j=0;j<4;j++){
    int cc = c0+j;
    float f = (r < R && cc < C) ? src[(size_t)r*C + cc] : 0.f;
    o[j] = f2b(f);
  }
  *(u16x4*)&dst[(size_t)r*Cpad + c0] = o;
}

// ---------------- adaLN: ada = silu(c) @ ada_w.T + ada_b  -> [4][6144] fp32 ----------------
__global__ __launch_bounds__(256) void ada_kernel(const float* __restrict__ c,
    const float* __restrict__ aw, const float* __restrict__ ab, float* __restrict__ ada)
{
  __shared__ float s[4][1024];
  int t = threadIdx.x;
#pragma unroll
  for (int i=0;i<16;i++){
    int idx = i*256 + t;
    float cv = c[idx];
    s[idx>>10][idx&1023] = cv/(1.f+__expf(-cv));
  }
  __syncthreads();
  int wid = t>>6, lane = t&63;
  int j = blockIdx.x*4 + wid;
  const f32x4* wp = (const f32x4*)(aw + (size_t)j*1024);
  float a0=0,a1=0,a2=0,a3=0;
#pragma unroll
  for (int i=0;i<4;i++){
    f32x4 wv = wp[i*64 + lane];
    int k0 = (i*64+lane)*4;
#pragma unroll
    for (int e=0;e<4;e++){
      float w = wv[e];
      a0 += w*s[0][k0+e]; a1 += w*s[1][k0+e]; a2 += w*s[2][k0+e]; a3 += w*s[3][k0+e];
    }
  }
#pragma unroll
  for (int mask=1; mask<64; mask<<=1){
    a0 += __shfl_xor(a0, mask); a1 += __shfl_xor(a1, mask);
    a2 += __shfl_xor(a2, mask); a3 += __shfl_xor(a3, mask);
  }
  if (lane==0){
    float bv = ab[j];
    ada[0*6144 + j] = a0 + bv;
    ada[1*6144 + j] = a1 + bv;
    ada[2*6144 + j] = a2 + bv;
    ada[3*6144 + j] = a3 + bv;
  }
}

// ---------------- fused RMSNorm + modulate -> bf16 ----------------
__global__ __launch_bounds__(256) void rms_mod(const float* __restrict__ x,
    const float* __restrict__ w, const float* __restrict__ ada, int chunkSh,
    u16* __restrict__ out)
{
  int row = blockIdx.x;
  int b = row>>10;
  int t = threadIdx.x;
  int wid = t>>6, lane = t&63;
  f32x4 v = *(const f32x4*)(x + (size_t)row*1024 + t*4);
  float ss = v[0]*v[0]+v[1]*v[1]+v[2]*v[2]+v[3]*v[3];
#pragma unroll
  for (int mask=1; mask<64; mask<<=1) ss += __shfl_xor(ss, mask);
  __shared__ float red[4];
  if (lane==0) red[wid]=ss;
  __syncthreads();
  float rinv = rsqrtf((red[0]+red[1]+red[2]+red[3])*(1.f/1024.f) + 1e-6f);
  int cc = t*4;
  const float* shp = ada + (size_t)b*6144 + (size_t)chunkSh*1024 + cc;
  u16x4 o;
#pragma unroll
  for (int jj=0;jj<4;jj++){
    float val = v[jj]*rinv*w[cc+jj];
    val = val*(1.f+shp[jj+1024]) + shp[jj];
    o[jj] = f2b(val);
  }
  *(u16x4*)&out[(size_t)row*1024 + cc] = o;
}

// ---------------- bf16 GEMM: C = A[M,K] * Bw[N,K]^T (+bias) ----------------
// EPI 0: store bf16 at outb, ld = N (padded). EPI 1: outf = xres + gate*(acc+bias), ld=1024.
template<int EPI>
__global__ __launch_bounds__(256,2) void gemm_bt(
    const u16* __restrict__ A, const u16* __restrict__ Bw, const float* __restrict__ bias,
    int N, int K, int nbias, u16* __restrict__ outb,
    const float* __restrict__ xres, const float* __restrict__ ada, int adaChunk,
    float* __restrict__ outf)
{
  __shared__ __align__(16) u16 As[128*32];
  __shared__ __align__(16) u16 Bs[128*32];
  int t = threadIdx.x;
  int wid = t>>6, lane = t&63;
  int lr = lane&15, lg = lane>>4;
  int bm = blockIdx.y, bn = blockIdx.x;
  const u16* pA = A  + (size_t)(bm*128 + (t>>2))*K + (t&3)*8;
  const u16* pB = Bw + (size_t)(bn*128 + (t>>2))*K + (t&3)*8;
  u16* lA = As + t*8;
  u16* lB = Bs + t*8;
  int wr = (wid>>1)*64, wc = (wid&1)*64;
  f32x4 acc[4][4] = {};
  for (int kk=0; kk<K; kk+=32){
    gload16(pA, lA);
    gload16(pA + (size_t)64*K, lA + 64*32);
    gload16(pB, lB);
    gload16(pB + (size_t)64*K, lB + 64*32);
    pA += 32; pB += 32;
    __syncthreads();
    bf16x8 af[4], bfr[4];
#pragma unroll
    for (int m=0;m<4;m++) af[m]  = *(const bf16x8*)&As[(wr + m*16 + lr)*32 + lg*8];
#pragma unroll
    for (int n=0;n<4;n++) bfr[n] = *(const bf16x8*)&Bs[(wc + n*16 + lr)*32 + lg*8];
#pragma unroll
    for (int m=0;m<4;m++)
#pragma unroll
      for (int n=0;n<4;n++)
        acc[m][n] = mfma16(af[m], bfr[n], acc[m][n]);
    __syncthreads();
  }
#pragma unroll
  for (int n=0;n<4;n++){
    int col = bn*128 + wc + n*16 + lr;
    float bv = (col < nbias) ? bias[col] : 0.f;
#pragma unroll
    for (int m=0;m<4;m++){
      int row0 = bm*128 + wr + m*16 + lg*4;
#pragma unroll
      for (int r=0;r<4;r++){
        int row = row0 + r;
        float v = acc[m][n][r] + bv;
        if constexpr (EPI==0){
          outb[(size_t)row*N + col] = f2b(v);
        } else {
          int bb = row>>10;
          float g = ada[(size_t)bb*6144 + (size_t)adaChunk*1024 + col];
          outf[(size_t)row*1024 + col] = xres[(size_t)row*1024 + col] + g*v;
        }
      }
    }
  }
}

// ---------------- qkv repack: rms-norm q,k per head (q pre-scaled by 1/8), v transposed ----------------
__global__ __launch_bounds__(256) void repack_qkv(const u16* __restrict__ qkvO,
    const float* __restrict__ qnw, const float* __restrict__ knw,
    u16* __restrict__ qO, u16* __restrict__ kO, u16* __restrict__ vtO)
{
  __shared__ u16 ldsv[64][64];
  int bh = blockIdx.y, b = bh>>4, h = bh&15;
  int n0 = blockIdx.x*64;
  int t = threadIdx.x;
  int nr = t>>2, qd = (t&3)*16;
  const u16* rowp = qkvO + (size_t)(b*1024 + n0 + nr)*3072;
  // Q: rms-norm * qn_w * (1/8)
  {
    u16x8 a0 = *(const u16x8*)(rowp + h*64 + qd);
    u16x8 a1 = *(const u16x8*)(rowp + h*64 + qd + 8);
    float f[16]; float ss=0;
#pragma unroll
    for (int jj=0;jj<8;jj++){ f[jj]=b2f(a0[jj]); f[8+jj]=b2f(a1[jj]); }
#pragma unroll
    for (int jj=0;jj<16;jj++) ss += f[jj]*f[jj];
    ss += __shfl_xor(ss,1); ss += __shfl_xor(ss,2);
    float rinv = rsqrtf(ss*(1.f/64.f)+1e-6f)*0.125f;
    u16x8 o0,o1;
#pragma unroll
    for (int jj=0;jj<8;jj++){ o0[jj]=f2b(f[jj]*rinv*qnw[qd+jj]); o1[jj]=f2b(f[8+jj]*rinv*qnw[qd+8+jj]); }
    u16* dst = qO + ((size_t)bh*1024 + n0 + nr)*64 + qd;
    *(u16x8*)dst = o0; *(u16x8*)(dst+8) = o1;
  }
  // K: rms-norm * kn_w
  {
    u16x8 a0 = *(const u16x8*)(rowp + 1024 + h*64 + qd);
    u16x8 a1 = *(const u16x8*)(rowp + 1024 + h*64 + qd + 8);
    float f[16]; float ss=0;
#pragma unroll
    for (int jj=0;jj<8;jj++){ f[jj]=b2f(a0[jj]); f[8+jj]=b2f(a1[jj]); }
#pragma unroll
    for (int jj=0;jj<16;jj++) ss += f[jj]*f[jj];
    ss += __shfl_xor(ss,1); ss += __shfl_xor(ss,2);
    float rinv = rsqrtf(ss*(1.f/64.f)+1e-6f);
    u16x8 o0,o1;
#pragma unroll
    for (int jj=0;jj<8;jj++){ o0[jj]=f2b(f[jj]*rinv*knw[qd+jj]); o1[jj]=f2b(f[8+jj]*rinv*knw[qd+8+jj]); }
    u16* dst = kO + ((size_t)bh*1024 + n0 + nr)*64 + qd;
    *(u16x8*)dst = o0; *(u16x8*)(dst+8) = o1;
  }
  // V: transpose to [bh][d][n]
  {
    u16x8 a0 = *(const u16x8*)(rowp + 2048 + h*64 + qd);
    u16x8 a1 = *(const u16x8*)(rowp + 2048 + h*64 + qd + 8);
#pragma unroll
    for (int jj=0;jj<8;jj++){ ldsv[qd+jj][nr] = a0[jj]; ldsv[qd+8+jj][nr] = a1[jj]; }
  }
  __syncthreads();
  {
    int d = t>>2, ns = (t&3)*16;
    u16x8 r0 = *(const u16x8*)&ldsv[d][ns];
    u16x8 r1 = *(const u16x8*)&ldsv[d][ns+8];
    u16* dst = vtO + ((size_t)bh*64 + d)*1024 + n0 + ns;
    *(u16x8*)dst = r0; *(u16x8*)(dst+8) = r1;
  }
}

// ---------------- flash attention (swapped QK^T, online softmax, LDS-free PV) ----------------
// grid (16 qblocks, 64 bh); 4 waves, 16 q-rows each. Softmax scale folded into q.
// PV consumes P directly from registers via 16x16x16 MFMA (A-frag layout == S^T layout).
__global__ __launch_bounds__(256) void attn_fwd(const u16* __restrict__ qO,
    const u16* __restrict__ kO, const u16* __restrict__ vtO, u16* __restrict__ o)
{
  int bh = blockIdx.y, b = bh>>4, h = bh&15;
  int wid = threadIdx.x>>6, lane = threadIdx.x&63;
  int lr = lane&15, lg = lane>>4;
  int q0 = blockIdx.x*64 + wid*16;
  const u16* qp = qO + ((size_t)bh*1024 + q0 + lr)*64 + lg*8;
  bf16x8 qf0 = *(const bf16x8*)qp;
  bf16x8 qf1 = *(const bf16x8*)(qp + 32);
  const u16* kb = kO  + (size_t)bh*1024*64;
  const u16* vb = vtO + (size_t)bh*64*1024;
  f32x4 oacc[4] = {};
  float mrun = -1e30f, lrun = 0.f;
  // preload K fragments for kk=0
  bf16x8 kc0, kc1, kc2, kc3;
  {
    const u16* kp = kb + (size_t)lr*64 + lg*8;
    kc0 = *(const bf16x8*)kp;
    kc1 = *(const bf16x8*)(kp + 32);
    kc2 = *(const bf16x8*)(kp + 16*64);
    kc3 = *(const bf16x8*)(kp + 16*64 + 32);
  }
#pragma unroll 2
  for (int kk=0; kk<1024; kk+=32){
    // S^T = K . Q^T : lane holds q=lr, kv = kk + {0,16} + lg*4 + r
    f32x4 s0 = {}, s1 = {};
    s0 = mfma16(kc0, qf0, s0); s0 = mfma16(kc1, qf1, s0);
    s1 = mfma16(kc2, qf0, s1); s1 = mfma16(kc3, qf1, s1);
    // prefetch next K tile (last iter reads 16B past kO into vt region: harmless, unused)
    {
      const u16* kp = kb + (size_t)(kk + 32 + lr)*64 + lg*8;
      kc0 = *(const bf16x8*)kp;
      kc1 = *(const bf16x8*)(kp + 32);
      kc2 = *(const bf16x8*)(kp + 16*64);
      kc3 = *(const bf16x8*)(kp + 16*64 + 32);
    }
    // V fragments for this step (independent of softmax -> latency hidden under it)
    bf16x4 vv0[4], vv1[4];
#pragma unroll
    for (int tt=0;tt<4;tt++){
      const u16* vp = vb + (size_t)(tt*16 + lr)*1024 + kk + lg*4;
      vv0[tt] = *(const bf16x4*)vp;
      vv1[tt] = *(const bf16x4*)(vp + 16);
    }
    // online softmax (per q-row = lr)
    float pm = s0[0];
#pragma unroll
    for (int r=1;r<4;r++) pm = fmaxf(pm, s0[r]);
#pragma unroll
    for (int r=0;r<4;r++) pm = fmaxf(pm, s1[r]);
    pm = fmaxf(pm, __shfl_xor(pm, 16));
    pm = fmaxf(pm, __shfl_xor(pm, 32));
    float mnew = fmaxf(mrun, pm);
    float alpha = __expf(mrun - mnew);
    float p0[4], p1[4]; float ls = 0.f;
#pragma unroll
    for (int r=0;r<4;r++){ p0[r]=__expf(s0[r]-mnew); p1[r]=__expf(s1[r]-mnew); ls += p0[r]+p1[r]; }
    ls += __shfl_xor(ls, 16); ls += __shfl_xor(ls, 32);
    lrun = lrun*alpha + ls; mrun = mnew;
    // P -> bf16 A-fragments for 16x16x16 MFMA (row=lr=q, k=lg*4+r -- exactly our layout)
    bf16x4 pa0, pa1;
#pragma unroll
    for (int r=0;r<4;r++){ pa0[r] = (__bf16)p0[r]; pa1[r] = (__bf16)p1[r]; }
    // rescale O by alpha (per q-row = lg*4+r) and accumulate PV
    float ar[4];
#pragma unroll
    for (int r=0;r<4;r++) ar[r] = __shfl(alpha, lg*4 + r);
#pragma unroll
    for (int tt=0;tt<4;tt++){
#pragma unroll
      for (int r=0;r<4;r++) oacc[tt][r] *= ar[r];
      oacc[tt] = mfma16k16(pa0, vv0[tt], oacc[tt]);
      oacc[tt] = mfma16k16(pa1, vv1[tt], oacc[tt]);
    }
  }
  float li = 1.f/lrun;
  float linv[4];
#pragma unroll
  for (int r=0;r<4;r++) linv[r] = __shfl(li, lg*4 + r);
#pragma unroll
  for (int tt=0;tt<4;tt++){
#pragma unroll
    for (int r=0;r<4;r++){
      int row = (b<<10) + blockIdx.x*64 + wid*16 + lg*4 + r;
      int col = h*64 + tt*16 + lr;
      o[(size_t)row*1024 + col] = f2b(oacc[tt][r]*linv[r]);
    }
  }
}

// ---------------- SwiGLU: hid = silu(x1)*x2, zero-padded to 2752 cols ----------------
__global__ __launch_bounds__(256) void swiglu_k(const u16* __restrict__ x12, u16* __restrict__ hid)
{
  int r = blockIdx.y;
  int c4 = blockIdx.x*256 + threadIdx.x;
  if (c4 >= 688) return;
  int cc = c4*4;
  const u16* rowp = x12 + (size_t)r*5504;
  u16x4 x1 = *(const u16x4*)(rowp + cc);
  u16x2 x2a = *(const u16x2*)(rowp + 2730 + cc);
  u16x2 x2b = *(const u16x2*)(rowp + 2730 + cc + 2);
  u16 x2v[4] = {x2a[0],x2a[1],x2b[0],x2b[1]};
  u16x4 o;
#pragma unroll
  for (int jj=0;jj<4;jj++){
    float a = b2f(x1[jj]);
    float g = silu_f(a)*b2f(x2v[jj]);
    o[jj] = (cc+jj < 2730) ? f2b(g) : (u16)0;
  }
  *(u16x4*)&hid[(size_t)r*2752 + cc] = o;
}

extern "C" void kernel_launch(void* const* d_in, const int* in_sizes, int n_in,
                              void* d_out, int out_size, void* d_ws, size_t ws_size,
                              hipStream_t stream)
{
  (void)in_sizes; (void)n_in; (void)out_size; (void)ws_size;
  const float* x    = (const float*)d_in[0];
  const float* c    = (const float*)d_in[1];
  const float* n1w  = (const float*)d_in[2];
  const float* cw   = (const float*)d_in[3];
  const float* cb   = (const float*)d_in[4];
  const float* qkvw = (const float*)d_in[5];
  const float* qkvb = (const float*)d_in[6];
  const float* qnw  = (const float*)d_in[7];
  const float* knw  = (const float*)d_in[8];
  const float* pw   = (const float*)d_in[9];
  const float* pb   = (const float*)d_in[10];
  const float* ew   = (const float*)d_in[11];
  const float* eb   = (const float*)d_in[12];
  const float* n2w  = (const float*)d_in[13];
  const float* w12w = (const float*)d_in[14];
  const float* w12b = (const float*)d_in[15];
  const float* w3w  = (const float*)d_in[16];
  const float* w3b  = (const float*)d_in[17];
  const float* adaw = (const float*)d_in[18];
  const float* adab = (const float*)d_in[19];
  float* out = (float*)d_out;
  char* ws = (char*)d_ws;
  auto U = [&](size_t off){ return (u16*)(ws + off); };
  auto F = [&](size_t off){ return (float*)(ws + off); };

  // weight conversions (bf16, zero-padded)
  convert_pad<<<dim3(1,1024), 256, 0, stream>>>(cw,   U(OFF_WC),   1024, 1024, 1024);
  convert_pad<<<dim3(1,3072), 256, 0, stream>>>(qkvw, U(OFF_WQKV), 3072, 1024, 1024);
  convert_pad<<<dim3(1,1024), 256, 0, stream>>>(pw,   U(OFF_WPROJ),1024, 1024, 1024);
  convert_pad<<<dim3(1,1024), 256, 0, stream>>>(ew,   U(OFF_WEXP), 1024, 1024, 1024);
  convert_pad<<<dim3(1,5504), 256, 0, stream>>>(w12w, U(OFF_WW12), 5460, 1024, 1024);
  convert_pad<<<dim3(3,1024), 256, 0, stream>>>(w3w,  U(OFF_WW3),  1024, 2730, 2752);

  ada_kernel<<<1536, 256, 0, stream>>>(c, adaw, adab, F(OFF_ADA));

  // attention branch
  rms_mod<<<4096, 256, 0, stream>>>(x, n1w, F(OFF_ADA), 0, U(OFF_H1));
  gemm_bt<0><<<dim3(8,32),  256, 0, stream>>>(U(OFF_H1), U(OFF_WC),   cb,   1024, 1024, 1024, U(OFF_HC),   nullptr, nullptr, 0, nullptr);
  gemm_bt<0><<<dim3(24,32), 256, 0, stream>>>(U(OFF_HC), U(OFF_WQKV), qkvb, 3072, 1024, 3072, U(OFF_QKVO), nullptr, nullptr, 0, nullptr);
  repack_qkv<<<dim3(16,64), 256, 0, stream>>>(U(OFF_QKVO), qnw, knw, U(OFF_Q), U(OFF_K), U(OFF_VT));
  attn_fwd<<<dim3(16,64), 256, 0, stream>>>(U(OFF_Q), U(OFF_K), U(OFF_VT), U(OFF_O));
  gemm_bt<0><<<dim3(8,32), 256, 0, stream>>>(U(OFF_O),  U(OFF_WPROJ), pb, 1024, 1024, 1024, U(OFF_PR), nullptr, nullptr, 0, nullptr);
  gemm_bt<1><<<dim3(8,32), 256, 0, stream>>>(U(OFF_PR), U(OFF_WEXP),  eb, 1024, 1024, 1024, nullptr, x, F(OFF_ADA), 2, F(OFF_X2));

  // FFN branch
  rms_mod<<<4096, 256, 0, stream>>>(F(OFF_X2), n2w, F(OFF_ADA), 3, U(OFF_H2));
  gemm_bt<0><<<dim3(43,32), 256, 0, stream>>>(U(OFF_H2), U(OFF_WW12), w12b, 5504, 1024, 5460, U(OFF_X12), nullptr, nullptr, 0, nullptr);
  swiglu_k<<<dim3(3,4096), 256, 0, stream>>>(U(OFF_X12), U(OFF_HID));
  gemm_bt<1><<<dim3(8,32), 256, 0, stream>>>(U(OFF_HID), U(OFF_WW3), w3b, 1024, 2752, 1024, nullptr, F(OFF_X2), F(OFF_ADA), 5, out);
}

// Round 3
// 512.527 us; speedup vs baseline: 1.0041x; 1.0041x over previous
//
#include <hip/hip_runtime.h>
#include <hip/hip_bf16.h>
#include <cstdint>
#include <cstddef>

typedef unsigned short u16;
typedef __bf16 bf16x8 __attribute__((ext_vector_type(8)));
typedef __bf16 bf16x4 __attribute__((ext_vector_type(4)));
typedef short   s16x4 __attribute__((ext_vector_type(4)));
typedef float    f32x4 __attribute__((ext_vector_type(4)));
typedef unsigned short u16x2 __attribute__((ext_vector_type(2)));
typedef unsigned short u16x4 __attribute__((ext_vector_type(4)));
typedef unsigned short u16x8 __attribute__((ext_vector_type(8)));

#define DEVI static __device__ __forceinline__

DEVI float b2f(u16 u){ union{unsigned i; float v;} x; x.i=((unsigned)u)<<16; return x.v; }
DEVI u16 f2b(float f){ union{float v; unsigned i;} x; x.v=f; unsigned r=x.i+0x7FFFu+((x.i>>16)&1u); return (u16)(r>>16); }
DEVI f32x4 mfma16(bf16x8 a, bf16x8 b, f32x4 c){ return __builtin_amdgcn_mfma_f32_16x16x32_bf16(a,b,c,0,0,0); }
DEVI f32x4 mfma16k16(bf16x4 a, bf16x4 b, f32x4 c){
#if __has_builtin(__builtin_amdgcn_mfma_f32_16x16x16_bf16)
  return __builtin_amdgcn_mfma_f32_16x16x16_bf16(a,b,c,0,0,0);
#elif __has_builtin(__builtin_amdgcn_mfma_f32_16x16x16bf16_1k)
  return __builtin_amdgcn_mfma_f32_16x16x16bf16_1k((s16x4)a,(s16x4)b,c,0,0,0);
#else
  asm volatile("v_mfma_f32_16x16x16_bf16 %0, %1, %2, %0" : "+v"(c) : "v"(a), "v"(b));
  return c;
#endif
}
DEVI float fexp2(float x){ return __builtin_amdgcn_exp2f(x); }
DEVI void gload16(const void* g, void* l){
  __builtin_amdgcn_global_load_lds((const __attribute__((address_space(1))) void*)g,
                                   (__attribute__((address_space(3))) void*)l, 16, 0, 0);
}
DEVI float silu_f(float x){ return x/(1.f+__expf(-x)); }

// ---------------- workspace layout (bytes) ----------------
static constexpr size_t OFF_WC   = 0;
static constexpr size_t OFF_WQKV = OFF_WC   + (size_t)1024*1024*2;
static constexpr size_t OFF_WPROJ= OFF_WQKV + (size_t)3072*1024*2;
static constexpr size_t OFF_WEXP = OFF_WPROJ+ (size_t)1024*1024*2;
static constexpr size_t OFF_WW12 = OFF_WEXP + (size_t)1024*1024*2;
static constexpr size_t OFF_WW3  = OFF_WW12 + (size_t)5504*1024*2;
static constexpr size_t OFF_ADA  = OFF_WW3  + (size_t)1024*2752*2;
static constexpr size_t OFF_X2   = OFF_ADA  + (size_t)4*6144*4;
static constexpr size_t OFF_P1   = OFF_X2   + (size_t)4096*1024*4;
static constexpr size_t OFF_H1   = OFF_P1;
static constexpr size_t OFF_HC   = OFF_H1   + (size_t)4096*1024*2;
static constexpr size_t OFF_QKVO = OFF_HC   + (size_t)4096*1024*2;
static constexpr size_t OFF_X12  = OFF_P1;                       // reuse: h1/hc/qkvO dead
static constexpr size_t OFF_P2   = OFF_P1   + (size_t)4096*5504*2;
static constexpr size_t OFF_Q    = OFF_P2;
static constexpr size_t OFF_K    = OFF_Q    + (size_t)64*1024*64*2;
static constexpr size_t OFF_VT   = OFF_K    + (size_t)64*1024*64*2;
static constexpr size_t OFF_O    = OFF_VT   + (size_t)64*1024*64*2;
static constexpr size_t OFF_PR   = OFF_O    + (size_t)4096*1024*2;
static constexpr size_t OFF_H2   = OFF_PR   + (size_t)4096*1024*2;
static constexpr size_t OFF_HID  = OFF_P2;                       // reuse: q/k/vt dead

// ---------------- fp32 -> bf16 weight conversion with zero padding ----------------
__global__ __launch_bounds__(256) void convert_pad(const float* __restrict__ src, u16* __restrict__ dst,
                                                   int R, int C, int Cpad)
{
  int r = blockIdx.y;
  int c0 = (blockIdx.x*256 + threadIdx.x)*4;
  if (c0 >= Cpad) return;
  u16x4 o;
#pragma unroll
  for (int j=0;j<4;j++){
    int cc = c0+j;
    float f = (r < R && cc < C) ? src[(size_t)r*C + cc] : 0.f;
    o[j] = f2b(f);
  }
  *(u16x4*)&dst[(size_t)r*Cpad + c0] = o;
}

// ---------------- adaLN: ada = silu(c) @ ada_w.T + ada_b  -> [4][6144] fp32 ----------------
__global__ __launch_bounds__(256) void ada_kernel(const float* __restrict__ c,
    const float* __restrict__ aw, const float* __restrict__ ab, float* __restrict__ ada)
{
  __shared__ float s[4][1024];
  int t = threadIdx.x;
#pragma unroll
  for (int i=0;i<16;i++){
    int idx = i*256 + t;
    float cv = c[idx];
    s[idx>>10][idx&1023] = cv/(1.f+__expf(-cv));
  }
  __syncthreads();
  int wid = t>>6, lane = t&63;
  int j = blockIdx.x*4 + wid;
  const f32x4* wp = (const f32x4*)(aw + (size_t)j*1024);
  float a0=0,a1=0,a2=0,a3=0;
#pragma unroll
  for (int i=0;i<4;i++){
    f32x4 wv = wp[i*64 + lane];
    int k0 = (i*64+lane)*4;
#pragma unroll
    for (int e=0;e<4;e++){
      float w = wv[e];
      a0 += w*s[0][k0+e]; a1 += w*s[1][k0+e]; a2 += w*s[2][k0+e]; a3 += w*s[3][k0+e];
    }
  }
#pragma unroll
  for (int mask=1; mask<64; mask<<=1){
    a0 += __shfl_xor(a0, mask); a1 += __shfl_xor(a1, mask);
    a2 += __shfl_xor(a2, mask); a3 += __shfl_xor(a3, mask);
  }
  if (lane==0){
    float bv = ab[j];
    ada[0*6144 + j] = a0 + bv;
    ada[1*6144 + j] = a1 + bv;
    ada[2*6144 + j] = a2 + bv;
    ada[3*6144 + j] = a3 + bv;
  }
}

// ---------------- fused RMSNorm + modulate -> bf16 ----------------
__global__ __launch_bounds__(256) void rms_mod(const float* __restrict__ x,
    const float* __restrict__ w, const float* __restrict__ ada, int chunkSh,
    u16* __restrict__ out)
{
  int row = blockIdx.x;
  int b = row>>10;
  int t = threadIdx.x;
  int wid = t>>6, lane = t&63;
  f32x4 v = *(const f32x4*)(x + (size_t)row*1024 + t*4);
  float ss = v[0]*v[0]+v[1]*v[1]+v[2]*v[2]+v[3]*v[3];
#pragma unroll
  for (int mask=1; mask<64; mask<<=1) ss += __shfl_xor(ss, mask);
  __shared__ float red[4];
  if (lane==0) red[wid]=ss;
  __syncthreads();
  float rinv = rsqrtf((red[0]+red[1]+red[2]+red[3])*(1.f/1024.f) + 1e-6f);
  int cc = t*4;
  const float* shp = ada + (size_t)b*6144 + (size_t)chunkSh*1024 + cc;
  u16x4 o;
#pragma unroll
  for (int jj=0;jj<4;jj++){
    float val = v[jj]*rinv*w[cc+jj];
    val = val*(1.f+shp[jj+1024]) + shp[jj];
    o[jj] = f2b(val);
  }
  *(u16x4*)&out[(size_t)row*1024 + cc] = o;
}

// ---------------- bf16 GEMM: C = A[M,K] * Bw[N,K]^T (+bias) ----------------
// EPI 0: store bf16 at outb, ld = N (padded). EPI 1: outf = xres + gate*(acc+bias), ld=1024.
template<int EPI>
__global__ __launch_bounds__(256,2) void gemm_bt(
    const u16* __restrict__ A, const u16* __restrict__ Bw, const float* __restrict__ bias,
    int N, int K, int nbias, u16* __restrict__ outb,
    const float* __restrict__ xres, const float* __restrict__ ada, int adaChunk,
    float* __restrict__ outf)
{
  __shared__ __align__(16) u16 As[128*32];
  __shared__ __align__(16) u16 Bs[128*32];
  int t = threadIdx.x;
  int wid = t>>6, lane = t&63;
  int lr = lane&15, lg = lane>>4;
  int bm = blockIdx.y, bn = blockIdx.x;
  const u16* pA = A  + (size_t)(bm*128 + (t>>2))*K + (t&3)*8;
  const u16* pB = Bw + (size_t)(bn*128 + (t>>2))*K + (t&3)*8;
  u16* lA = As + t*8;
  u16* lB = Bs + t*8;
  int wr = (wid>>1)*64, wc = (wid&1)*64;
  f32x4 acc[4][4] = {};
  for (int kk=0; kk<K; kk+=32){
    gload16(pA, lA);
    gload16(pA + (size_t)64*K, lA + 64*32);
    gload16(pB, lB);
    gload16(pB + (size_t)64*K, lB + 64*32);
    pA += 32; pB += 32;
    __syncthreads();
    bf16x8 af[4], bfr[4];
#pragma unroll
    for (int m=0;m<4;m++) af[m]  = *(const bf16x8*)&As[(wr + m*16 + lr)*32 + lg*8];
#pragma unroll
    for (int n=0;n<4;n++) bfr[n] = *(const bf16x8*)&Bs[(wc + n*16 + lr)*32 + lg*8];
#pragma unroll
    for (int m=0;m<4;m++)
#pragma unroll
      for (int n=0;n<4;n++)
        acc[m][n] = mfma16(af[m], bfr[n], acc[m][n]);
    __syncthreads();
  }
#pragma unroll
  for (int n=0;n<4;n++){
    int col = bn*128 + wc + n*16 + lr;
    float bv = (col < nbias) ? bias[col] : 0.f;
#pragma unroll
    for (int m=0;m<4;m++){
      int row0 = bm*128 + wr + m*16 + lg*4;
#pragma unroll
      for (int r=0;r<4;r++){
        int row = row0 + r;
        float v = acc[m][n][r] + bv;
        if constexpr (EPI==0){
          outb[(size_t)row*N + col] = f2b(v);
        } else {
          int bb = row>>10;
          float g = ada[(size_t)bb*6144 + (size_t)adaChunk*1024 + col];
          outf[(size_t)row*1024 + col] = xres[(size_t)row*1024 + col] + g*v;
        }
      }
    }
  }
}

// ---------------- qkv repack: rms-norm q,k per head, v transposed ----------------
// q pre-scaled by (1/8)*log2(e) so attention softmax runs in exp2 domain.
__global__ __launch_bounds__(256) void repack_qkv(const u16* __restrict__ qkvO,
    const float* __restrict__ qnw, const float* __restrict__ knw,
    u16* __restrict__ qO, u16* __restrict__ kO, u16* __restrict__ vtO)
{
  __shared__ u16 ldsv[64][64];
  int bh = blockIdx.y, b = bh>>4, h = bh&15;
  int n0 = blockIdx.x*64;
  int t = threadIdx.x;
  int nr = t>>2, qd = (t&3)*16;
  const u16* rowp = qkvO + (size_t)(b*1024 + n0 + nr)*3072;
  // Q: rms-norm * qn_w * (1/8)*log2e
  {
    u16x8 a0 = *(const u16x8*)(rowp + h*64 + qd);
    u16x8 a1 = *(const u16x8*)(rowp + h*64 + qd + 8);
    float f[16]; float ss=0;
#pragma unroll
    for (int jj=0;jj<8;jj++){ f[jj]=b2f(a0[jj]); f[8+jj]=b2f(a1[jj]); }
#pragma unroll
    for (int jj=0;jj<16;jj++) ss += f[jj]*f[jj];
    ss += __shfl_xor(ss,1); ss += __shfl_xor(ss,2);
    float rinv = rsqrtf(ss*(1.f/64.f)+1e-6f)*0.125f*1.44269504089f;
    u16x8 o0,o1;
#pragma unroll
    for (int jj=0;jj<8;jj++){ o0[jj]=f2b(f[jj]*rinv*qnw[qd+jj]); o1[jj]=f2b(f[8+jj]*rinv*qnw[qd+8+jj]); }
    u16* dst = qO + ((size_t)bh*1024 + n0 + nr)*64 + qd;
    *(u16x8*)dst = o0; *(u16x8*)(dst+8) = o1;
  }
  // K: rms-norm * kn_w
  {
    u16x8 a0 = *(const u16x8*)(rowp + 1024 + h*64 + qd);
    u16x8 a1 = *(const u16x8*)(rowp + 1024 + h*64 + qd + 8);
    float f[16]; float ss=0;
#pragma unroll
    for (int jj=0;jj<8;jj++){ f[jj]=b2f(a0[jj]); f[8+jj]=b2f(a1[jj]); }
#pragma unroll
    for (int jj=0;jj<16;jj++) ss += f[jj]*f[jj];
    ss += __shfl_xor(ss,1); ss += __shfl_xor(ss,2);
    float rinv = rsqrtf(ss*(1.f/64.f)+1e-6f);
    u16x8 o0,o1;
#pragma unroll
    for (int jj=0;jj<8;jj++){ o0[jj]=f2b(f[jj]*rinv*knw[qd+jj]); o1[jj]=f2b(f[8+jj]*rinv*knw[qd+8+jj]); }
    u16* dst = kO + ((size_t)bh*1024 + n0 + nr)*64 + qd;
    *(u16x8*)dst = o0; *(u16x8*)(dst+8) = o1;
  }
  // V: transpose to [bh][d][n]
  {
    u16x8 a0 = *(const u16x8*)(rowp + 2048 + h*64 + qd);
    u16x8 a1 = *(const u16x8*)(rowp + 2048 + h*64 + qd + 8);
#pragma unroll
    for (int jj=0;jj<8;jj++){ ldsv[qd+jj][nr] = a0[jj]; ldsv[qd+8+jj][nr] = a1[jj]; }
  }
  __syncthreads();
  {
    int d = t>>2, ns = (t&3)*16;
    u16x8 r0 = *(const u16x8*)&ldsv[d][ns];
    u16x8 r1 = *(const u16x8*)&ldsv[d][ns+8];
    u16* dst = vtO + ((size_t)bh*64 + d)*1024 + n0 + ns;
    *(u16x8*)dst = r0; *(u16x8*)(dst+8) = r1;
  }
}

// ---------------- flash attention: split-K x2, 8 waves/block, defer-max, exp2 domain ----------------
// grid (16 qgroups of 64 rows, 64 bh), block 512. Wave w: qtile = w>>1 (16 rows), kv-half = w&1 (512 kv).
// Halves merge in LDS at the end. PV consumes P from registers via 16x16x16 MFMA.
__global__ __launch_bounds__(512) void attn_fwd(const u16* __restrict__ qO,
    const u16* __restrict__ kO, const u16* __restrict__ vtO, u16* __restrict__ o)
{
  __shared__ __align__(16) float obuf[4][64][16];   // [pair][lane][tt*4+r] partial O (half 1)
  __shared__ __align__(16) float mlb[4][2][2][16];  // [pair][half][{m,l}][row]
  int bh = blockIdx.y, b = bh>>4, h = bh&15;
  int w = threadIdx.x>>6, lane = threadIdx.x&63;
  int pair = w>>1, half = w&1;
  int lr = lane&15, lg = lane>>4;
  int q0 = blockIdx.x*64 + pair*16;
  const u16* qp = qO + ((size_t)bh*1024 + q0 + lr)*64 + lg*8;
  bf16x8 qf0 = *(const bf16x8*)qp;
  bf16x8 qf1 = *(const bf16x8*)(qp + 32);
  const u16* kb = kO  + ((size_t)bh*1024 + half*512)*64;
  const u16* vb = vtO + (size_t)bh*64*1024 + half*512;
  f32x4 oacc[4] = {};
  float mrun = -3.0e38f, lrun = 0.f;
  for (int kk=0; kk<512; kk+=32){
    const u16* kp = kb + (size_t)(kk + lr)*64 + lg*8;
    bf16x8 k00 = *(const bf16x8*)kp;
    bf16x8 k01 = *(const bf16x8*)(kp + 32);
    bf16x8 k10 = *(const bf16x8*)(kp + 16*64);
    bf16x8 k11 = *(const bf16x8*)(kp + 16*64 + 32);
    // S^T = K . Q^T : lane holds q=lr, kv = kk + {0,16} + lg*4 + r  (exp2 units)
    f32x4 s0 = {}, s1 = {};
    s0 = mfma16(k00, qf0, s0); s0 = mfma16(k01, qf1, s0);
    s1 = mfma16(k10, qf0, s1); s1 = mfma16(k11, qf1, s1);
    // V fragments (independent of softmax -> latency hidden under it)
    bf16x4 vv0[4], vv1[4];
#pragma unroll
    for (int tt=0;tt<4;tt++){
      const u16* vp = vb + (size_t)(tt*16 + lr)*1024 + kk + lg*4;
      vv0[tt] = *(const bf16x4*)vp;
      vv1[tt] = *(const bf16x4*)(vp + 16);
    }
    // per-q-row tile max
    float pm = fmaxf(fmaxf(fmaxf(s0[0],s0[1]),fmaxf(s0[2],s0[3])),
                     fmaxf(fmaxf(s1[0],s1[1]),fmaxf(s1[2],s1[3])));
    pm = fmaxf(pm, __shfl_xor(pm, 16));
    pm = fmaxf(pm, __shfl_xor(pm, 32));
    // defer-max: only rescale when the running max grew by > 8 (P bounded by 2^8)
    if (__any(pm > mrun + 8.f)){
      float mnew = fmaxf(mrun, pm);
      float alpha = fexp2(mrun - mnew);
      mrun = mnew;
      lrun *= alpha;
      float ar[4];
#pragma unroll
      for (int r=0;r<4;r++) ar[r] = __shfl(alpha, lg*4 + r);
#pragma unroll
      for (int tt=0;tt<4;tt++)
#pragma unroll
        for (int r=0;r<4;r++) oacc[tt][r] *= ar[r];
    }
    float p0[4], p1[4]; float ls = 0.f;
#pragma unroll
    for (int r=0;r<4;r++){ p0[r]=fexp2(s0[r]-mrun); p1[r]=fexp2(s1[r]-mrun); ls += p0[r]+p1[r]; }
    ls += __shfl_xor(ls, 16); ls += __shfl_xor(ls, 32);
    lrun += ls;
    bf16x4 pa0, pa1;
#pragma unroll
    for (int r=0;r<4;r++){ pa0[r] = (__bf16)p0[r]; pa1[r] = (__bf16)p1[r]; }
#pragma unroll
    for (int tt=0;tt<4;tt++){
      oacc[tt] = mfma16k16(pa0, vv0[tt], oacc[tt]);
      oacc[tt] = mfma16k16(pa1, vv1[tt], oacc[tt]);
    }
  }
  // ---- merge the two kv-halves via LDS ----
  if (lg==0){ mlb[pair][half][0][lr] = mrun; mlb[pair][half][1][lr] = lrun; }
  __syncthreads();
  f32x4 m0 = *(const f32x4*)&mlb[pair][0][0][lg*4];
  f32x4 l0 = *(const f32x4*)&mlb[pair][0][1][lg*4];
  f32x4 m1 = *(const f32x4*)&mlb[pair][1][0][lg*4];
  f32x4 l1 = *(const f32x4*)&mlb[pair][1][1][lg*4];
  f32x4 fh;
#pragma unroll
  for (int r=0;r<4;r++){
    float m = fmaxf(m0[r], m1[r]);
    float e0 = fexp2(m0[r]-m), e1 = fexp2(m1[r]-m);
    float li = 1.f/(l0[r]*e0 + l1[r]*e1);
    fh[r] = (half ? e1 : e0)*li;
  }
  if (half==1){
#pragma unroll
    for (int tt=0;tt<4;tt++){
      f32x4 t;
#pragma unroll
      for (int r=0;r<4;r++) t[r] = oacc[tt][r]*fh[r];
      *(f32x4*)&obuf[pair][lane][tt*4] = t;
    }
  }
  __syncthreads();
  if (half==0){
#pragma unroll
    for (int tt=0;tt<4;tt++){
      f32x4 p = *(const f32x4*)&obuf[pair][lane][tt*4];
#pragma unroll
      for (int r=0;r<4;r++){
        int row = (b<<10) + q0 + lg*4 + r;
        int col = h*64 + tt*16 + lr;
        o[(size_t)row*1024 + col] = f2b(oacc[tt][r]*fh[r] + p[r]);
      }
    }
  }
}

// ---------------- SwiGLU: hid = silu(x1)*x2, zero-padded to 2752 cols ----------------
__global__ __launch_bounds__(256) void swiglu_k(const u16* __restrict__ x12, u16* __restrict__ hid)
{
  int r = blockIdx.y;
  int c4 = blockIdx.x*256 + threadIdx.x;
  if (c4 >= 688) return;
  int cc = c4*4;
  const u16* rowp = x12 + (size_t)r*5504;
  u16x4 x1 = *(const u16x4*)(rowp + cc);
  u16x2 x2a = *(const u16x2*)(rowp + 2730 + cc);
  u16x2 x2b = *(const u16x2*)(rowp + 2730 + cc + 2);
  u16 x2v[4] = {x2a[0],x2a[1],x2b[0],x2b[1]};
  u16x4 o;
#pragma unroll
  for (int jj=0;jj<4;jj++){
    float a = b2f(x1[jj]);
    float g = silu_f(a)*b2f(x2v[jj]);
    o[jj] = (cc+jj < 2730) ? f2b(g) : (u16)0;
  }
  *(u16x4*)&hid[(size_t)r*2752 + cc] = o;
}

extern "C" void kernel_launch(void* const* d_in, const int* in_sizes, int n_in,
                              void* d_out, int out_size, void* d_ws, size_t ws_size,
                              hipStream_t stream)
{
  (void)in_sizes; (void)n_in; (void)out_size; (void)ws_size;
  const float* x    = (const float*)d_in[0];
  const float* c    = (const float*)d_in[1];
  const float* n1w  = (const float*)d_in[2];
  const float* cw   = (const float*)d_in[3];
  const float* cb   = (const float*)d_in[4];
  const float* qkvw = (const float*)d_in[5];
  const float* qkvb = (const float*)d_in[6];
  const float* qnw  = (const float*)d_in[7];
  const float* knw  = (const float*)d_in[8];
  const float* pw   = (const float*)d_in[9];
  const float* pb   = (const float*)d_in[10];
  const float* ew   = (const float*)d_in[11];
  const float* eb   = (const float*)d_in[12];
  const float* n2w  = (const float*)d_in[13];
  const float* w12w = (const float*)d_in[14];
  const float* w12b = (const float*)d_in[15];
  const float* w3w  = (const float*)d_in[16];
  const float* w3b  = (const float*)d_in[17];
  const float* adaw = (const float*)d_in[18];
  const float* adab = (const float*)d_in[19];
  float* out = (float*)d_out;
  char* ws = (char*)d_ws;
  auto U = [&](size_t off){ return (u16*)(ws + off); };
  auto F = [&](size_t off){ return (float*)(ws + off); };

  // weight conversions (bf16, zero-padded)
  convert_pad<<<dim3(1,1024), 256, 0, stream>>>(cw,   U(OFF_WC),   1024, 1024, 1024);
  convert_pad<<<dim3(1,3072), 256, 0, stream>>>(qkvw, U(OFF_WQKV), 3072, 1024, 1024);
  convert_pad<<<dim3(1,1024), 256, 0, stream>>>(pw,   U(OFF_WPROJ),1024, 1024, 1024);
  convert_pad<<<dim3(1,1024), 256, 0, stream>>>(ew,   U(OFF_WEXP), 1024, 1024, 1024);
  convert_pad<<<dim3(1,5504), 256, 0, stream>>>(w12w, U(OFF_WW12), 5460, 1024, 1024);
  convert_pad<<<dim3(3,1024), 256, 0, stream>>>(w3w,  U(OFF_WW3),  1024, 2730, 2752);

  ada_kernel<<<1536, 256, 0, stream>>>(c, adaw, adab, F(OFF_ADA));

  // attention branch
  rms_mod<<<4096, 256, 0, stream>>>(x, n1w, F(OFF_ADA), 0, U(OFF_H1));
  gemm_bt<0><<<dim3(8,32),  256, 0, stream>>>(U(OFF_H1), U(OFF_WC),   cb,   1024, 1024, 1024, U(OFF_HC),   nullptr, nullptr, 0, nullptr);
  gemm_bt<0><<<dim3(24,32), 256, 0, stream>>>(U(OFF_HC), U(OFF_WQKV), qkvb, 3072, 1024, 3072, U(OFF_QKVO), nullptr, nullptr, 0, nullptr);
  repack_qkv<<<dim3(16,64), 256, 0, stream>>>(U(OFF_QKVO), qnw, knw, U(OFF_Q), U(OFF_K), U(OFF_VT));
  attn_fwd<<<dim3(16,64), 512, 0, stream>>>(U(OFF_Q), U(OFF_K), U(OFF_VT), U(OFF_O));
  gemm_bt<0><<<dim3(8,32), 256, 0, stream>>>(U(OFF_O),  U(OFF_WPROJ), pb, 1024, 1024, 1024, U(OFF_PR), nullptr, nullptr, 0, nullptr);
  gemm_bt<1><<<dim3(8,32), 256, 0, stream>>>(U(OFF_PR), U(OFF_WEXP),  eb, 1024, 1024, 1024, nullptr, x, F(OFF_ADA), 2, F(OFF_X2));

  // FFN branch
  rms_mod<<<4096, 256, 0, stream>>>(F(OFF_X2), n2w, F(OFF_ADA), 3, U(OFF_H2));
  gemm_bt<0><<<dim3(43,32), 256, 0, stream>>>(U(OFF_H2), U(OFF_WW12), w12b, 5504, 1024, 5460, U(OFF_X12), nullptr, nullptr, 0, nullptr);
  swiglu_k<<<dim3(3,4096), 256, 0, stream>>>(U(OFF_X12), U(OFF_HID));
  gemm_bt<1><<<dim3(8,32), 256, 0, stream>>>(U(OFF_HID), U(OFF_WW3), w3b, 1024, 2752, 1024, nullptr, F(OFF_X2), F(OFF_ADA), 5, out);
}

// Round 4
// 391.103 us; speedup vs baseline: 1.3158x; 1.3105x over previous
//
#include <hip/hip_runtime.h>
#include <hip/hip_bf16.h>
#include <cstdint>
#include <cstddef>

typedef unsigned short u16;
typedef __bf16 bf16x8 __attribute__((ext_vector_type(8)));
typedef __bf16 bf16x4 __attribute__((ext_vector_type(4)));
typedef short   s16x4 __attribute__((ext_vector_type(4)));
typedef float    f32x4 __attribute__((ext_vector_type(4)));
typedef unsigned short u16x2 __attribute__((ext_vector_type(2)));
typedef unsigned short u16x4 __attribute__((ext_vector_type(4)));
typedef unsigned short u16x8 __attribute__((ext_vector_type(8)));

#define DEVI static __device__ __forceinline__

DEVI float b2f(u16 u){ union{unsigned i; float v;} x; x.i=((unsigned)u)<<16; return x.v; }
DEVI u16 f2b(float f){ union{float v; unsigned i;} x; x.v=f; unsigned r=x.i+0x7FFFu+((x.i>>16)&1u); return (u16)(r>>16); }
DEVI f32x4 mfma16(bf16x8 a, bf16x8 b, f32x4 c){ return __builtin_amdgcn_mfma_f32_16x16x32_bf16(a,b,c,0,0,0); }
DEVI f32x4 mfma16k16(bf16x4 a, bf16x4 b, f32x4 c){
#if __has_builtin(__builtin_amdgcn_mfma_f32_16x16x16_bf16)
  return __builtin_amdgcn_mfma_f32_16x16x16_bf16(a,b,c,0,0,0);
#elif __has_builtin(__builtin_amdgcn_mfma_f32_16x16x16bf16_1k)
  return __builtin_amdgcn_mfma_f32_16x16x16bf16_1k((s16x4)a,(s16x4)b,c,0,0,0);
#else
  asm volatile("v_mfma_f32_16x16x16_bf16 %0, %1, %2, %0" : "+v"(c) : "v"(a), "v"(b));
  return c;
#endif
}
DEVI float fexp2(float x){ return __builtin_amdgcn_exp2f(x); }
DEVI void gload16(const void* g, void* l){
  __builtin_amdgcn_global_load_lds((const __attribute__((address_space(1))) void*)g,
                                   (__attribute__((address_space(3))) void*)l, 16, 0, 0);
}
DEVI float silu_f(float x){ return x/(1.f+__expf(-x)); }

// ---------------- workspace layout (bytes) ----------------
static constexpr size_t OFF_WC   = 0;
static constexpr size_t OFF_WQKV = OFF_WC   + (size_t)1024*1024*2;
static constexpr size_t OFF_WPROJ= OFF_WQKV + (size_t)3072*1024*2;
static constexpr size_t OFF_WEXP = OFF_WPROJ+ (size_t)1024*1024*2;
static constexpr size_t OFF_WW12 = OFF_WEXP + (size_t)1024*1024*2;
static constexpr size_t OFF_WW3  = OFF_WW12 + (size_t)5504*1024*2;
static constexpr size_t OFF_ADA  = OFF_WW3  + (size_t)1024*2752*2;
static constexpr size_t OFF_X2   = OFF_ADA  + (size_t)4*6144*4;
static constexpr size_t OFF_P1   = OFF_X2   + (size_t)4096*1024*4;
static constexpr size_t OFF_H1   = OFF_P1;
static constexpr size_t OFF_HC   = OFF_H1   + (size_t)4096*1024*2;
static constexpr size_t OFF_QKVO = OFF_HC   + (size_t)4096*1024*2;
static constexpr size_t OFF_X12  = OFF_P1;                       // reuse: h1/hc/qkvO dead
static constexpr size_t OFF_P2   = OFF_P1   + (size_t)4096*5504*2;
static constexpr size_t OFF_Q    = OFF_P2;
static constexpr size_t OFF_K    = OFF_Q    + (size_t)64*1024*64*2;
static constexpr size_t OFF_VT   = OFF_K    + (size_t)64*1024*64*2;
static constexpr size_t OFF_O    = OFF_VT   + (size_t)64*1024*64*2;
static constexpr size_t OFF_PR   = OFF_O    + (size_t)4096*1024*2;
static constexpr size_t OFF_H2   = OFF_PR   + (size_t)4096*1024*2;
static constexpr size_t OFF_HID  = OFF_P2;                       // reuse: q/k/vt dead

// ---------------- fp32 -> bf16 weight conversion with zero padding ----------------
__global__ __launch_bounds__(256) void convert_pad(const float* __restrict__ src, u16* __restrict__ dst,
                                                   int R, int C, int Cpad)
{
  int r = blockIdx.y;
  int c0 = (blockIdx.x*256 + threadIdx.x)*4;
  if (c0 >= Cpad) return;
  u16x4 o;
#pragma unroll
  for (int j=0;j<4;j++){
    int cc = c0+j;
    float f = (r < R && cc < C) ? src[(size_t)r*C + cc] : 0.f;
    o[j] = f2b(f);
  }
  *(u16x4*)&dst[(size_t)r*Cpad + c0] = o;
}

// ---------------- adaLN: ada = silu(c) @ ada_w.T + ada_b  -> [4][6144] fp32 ----------------
__global__ __launch_bounds__(256) void ada_kernel(const float* __restrict__ c,
    const float* __restrict__ aw, const float* __restrict__ ab, float* __restrict__ ada)
{
  __shared__ float s[4][1024];
  int t = threadIdx.x;
#pragma unroll
  for (int i=0;i<16;i++){
    int idx = i*256 + t;
    float cv = c[idx];
    s[idx>>10][idx&1023] = cv/(1.f+__expf(-cv));
  }
  __syncthreads();
  int wid = t>>6, lane = t&63;
  int j = blockIdx.x*4 + wid;
  const f32x4* wp = (const f32x4*)(aw + (size_t)j*1024);
  float a0=0,a1=0,a2=0,a3=0;
#pragma unroll
  for (int i=0;i<4;i++){
    f32x4 wv = wp[i*64 + lane];
    int k0 = (i*64+lane)*4;
#pragma unroll
    for (int e=0;e<4;e++){
      float w = wv[e];
      a0 += w*s[0][k0+e]; a1 += w*s[1][k0+e]; a2 += w*s[2][k0+e]; a3 += w*s[3][k0+e];
    }
  }
#pragma unroll
  for (int mask=1; mask<64; mask<<=1){
    a0 += __shfl_xor(a0, mask); a1 += __shfl_xor(a1, mask);
    a2 += __shfl_xor(a2, mask); a3 += __shfl_xor(a3, mask);
  }
  if (lane==0){
    float bv = ab[j];
    ada[0*6144 + j] = a0 + bv;
    ada[1*6144 + j] = a1 + bv;
    ada[2*6144 + j] = a2 + bv;
    ada[3*6144 + j] = a3 + bv;
  }
}

// ---------------- fused RMSNorm + modulate -> bf16 ----------------
__global__ __launch_bounds__(256) void rms_mod(const float* __restrict__ x,
    const float* __restrict__ w, const float* __restrict__ ada, int chunkSh,
    u16* __restrict__ out)
{
  int row = blockIdx.x;
  int b = row>>10;
  int t = threadIdx.x;
  int wid = t>>6, lane = t&63;
  f32x4 v = *(const f32x4*)(x + (size_t)row*1024 + t*4);
  float ss = v[0]*v[0]+v[1]*v[1]+v[2]*v[2]+v[3]*v[3];
#pragma unroll
  for (int mask=1; mask<64; mask<<=1) ss += __shfl_xor(ss, mask);
  __shared__ float red[4];
  if (lane==0) red[wid]=ss;
  __syncthreads();
  float rinv = rsqrtf((red[0]+red[1]+red[2]+red[3])*(1.f/1024.f) + 1e-6f);
  int cc = t*4;
  const float* shp = ada + (size_t)b*6144 + (size_t)chunkSh*1024 + cc;
  u16x4 o;
#pragma unroll
  for (int jj=0;jj<4;jj++){
    float val = v[jj]*rinv*w[cc+jj];
    val = val*(1.f+shp[jj+1024]) + shp[jj];
    o[jj] = f2b(val);
  }
  *(u16x4*)&out[(size_t)row*1024 + cc] = o;
}

// ---------------- bf16 GEMM: C = A[M,K] * Bw[N,K]^T (+bias) ----------------
// EPI 0: store bf16 at outb, ld = N (padded). EPI 1: outf = xres + gate*(acc+bias), ld=1024.
template<int EPI>
__global__ __launch_bounds__(256,2) void gemm_bt(
    const u16* __restrict__ A, const u16* __restrict__ Bw, const float* __restrict__ bias,
    int N, int K, int nbias, u16* __restrict__ outb,
    const float* __restrict__ xres, const float* __restrict__ ada, int adaChunk,
    float* __restrict__ outf)
{
  __shared__ __align__(16) u16 As[128*32];
  __shared__ __align__(16) u16 Bs[128*32];
  int t = threadIdx.x;
  int wid = t>>6, lane = t&63;
  int lr = lane&15, lg = lane>>4;
  int bm = blockIdx.y, bn = blockIdx.x;
  const u16* pA = A  + (size_t)(bm*128 + (t>>2))*K + (t&3)*8;
  const u16* pB = Bw + (size_t)(bn*128 + (t>>2))*K + (t&3)*8;
  u16* lA = As + t*8;
  u16* lB = Bs + t*8;
  int wr = (wid>>1)*64, wc = (wid&1)*64;
  f32x4 acc[4][4] = {};
  for (int kk=0; kk<K; kk+=32){
    gload16(pA, lA);
    gload16(pA + (size_t)64*K, lA + 64*32);
    gload16(pB, lB);
    gload16(pB + (size_t)64*K, lB + 64*32);
    pA += 32; pB += 32;
    __syncthreads();
    bf16x8 af[4], bfr[4];
#pragma unroll
    for (int m=0;m<4;m++) af[m]  = *(const bf16x8*)&As[(wr + m*16 + lr)*32 + lg*8];
#pragma unroll
    for (int n=0;n<4;n++) bfr[n] = *(const bf16x8*)&Bs[(wc + n*16 + lr)*32 + lg*8];
#pragma unroll
    for (int m=0;m<4;m++)
#pragma unroll
      for (int n=0;n<4;n++)
        acc[m][n] = mfma16(af[m], bfr[n], acc[m][n]);
    __syncthreads();
  }
#pragma unroll
  for (int n=0;n<4;n++){
    int col = bn*128 + wc + n*16 + lr;
    float bv = (col < nbias) ? bias[col] : 0.f;
#pragma unroll
    for (int m=0;m<4;m++){
      int row0 = bm*128 + wr + m*16 + lg*4;
#pragma unroll
      for (int r=0;r<4;r++){
        int row = row0 + r;
        float v = acc[m][n][r] + bv;
        if constexpr (EPI==0){
          outb[(size_t)row*N + col] = f2b(v);
        } else {
          int bb = row>>10;
          float g = ada[(size_t)bb*6144 + (size_t)adaChunk*1024 + col];
          outf[(size_t)row*1024 + col] = xres[(size_t)row*1024 + col] + g*v;
        }
      }
    }
  }
}

// ---------------- qkv repack: rms-norm q,k per head, fragment-major K/V for attention ----------------
// q pre-scaled by (1/8)*log2(e) so attention softmax runs in exp2 domain.
// K frag layout: [bh][kv16-tile][c=2][lane=64][8 u16]  (lane = lg*16+lr; holds K[kv=t16*16+lr][d=c*32+lg*8 ..+8])
// V frag layout: [bh][kv32-tile][tt=4][lane=64][2 half][4 u16] (lane=lg*16+lr; holds V[kv=m*32+half*16+lg*4+e][d=tt*16+lr])
__global__ __launch_bounds__(256) void repack_qkv(const u16* __restrict__ qkvO,
    const float* __restrict__ qnw, const float* __restrict__ knw,
    u16* __restrict__ qO, u16* __restrict__ kO, u16* __restrict__ vO)
{
  __shared__ u16 ldsv[64][64];
  int bh = blockIdx.y, b = bh>>4, h = bh&15;
  int n0 = blockIdx.x*64;
  int t = threadIdx.x;
  int nr = t>>2, qd = (t&3)*16;
  const u16* rowp = qkvO + (size_t)(b*1024 + n0 + nr)*3072;
  // Q: rms-norm * qn_w * (1/8)*log2e  (standard [bh][n][d] layout)
  {
    u16x8 a0 = *(const u16x8*)(rowp + h*64 + qd);
    u16x8 a1 = *(const u16x8*)(rowp + h*64 + qd + 8);
    float f[16]; float ss=0;
#pragma unroll
    for (int jj=0;jj<8;jj++){ f[jj]=b2f(a0[jj]); f[8+jj]=b2f(a1[jj]); }
#pragma unroll
    for (int jj=0;jj<16;jj++) ss += f[jj]*f[jj];
    ss += __shfl_xor(ss,1); ss += __shfl_xor(ss,2);
    float rinv = rsqrtf(ss*(1.f/64.f)+1e-6f)*0.125f*1.44269504089f;
    u16x8 o0,o1;
#pragma unroll
    for (int jj=0;jj<8;jj++){ o0[jj]=f2b(f[jj]*rinv*qnw[qd+jj]); o1[jj]=f2b(f[8+jj]*rinv*qnw[qd+8+jj]); }
    u16* dst = qO + ((size_t)bh*1024 + n0 + nr)*64 + qd;
    *(u16x8*)dst = o0; *(u16x8*)(dst+8) = o1;
  }
  // K: rms-norm * kn_w -> fragment-major
  {
    u16x8 a0 = *(const u16x8*)(rowp + 1024 + h*64 + qd);
    u16x8 a1 = *(const u16x8*)(rowp + 1024 + h*64 + qd + 8);
    float f[16]; float ss=0;
#pragma unroll
    for (int jj=0;jj<8;jj++){ f[jj]=b2f(a0[jj]); f[8+jj]=b2f(a1[jj]); }
#pragma unroll
    for (int jj=0;jj<16;jj++) ss += f[jj]*f[jj];
    ss += __shfl_xor(ss,1); ss += __shfl_xor(ss,2);
    float rinv = rsqrtf(ss*(1.f/64.f)+1e-6f);
    u16x8 o0,o1;
#pragma unroll
    for (int jj=0;jj<8;jj++){ o0[jj]=f2b(f[jj]*rinv*knw[qd+jj]); o1[jj]=f2b(f[8+jj]*rinv*knw[qd+8+jj]); }
    int t16 = (n0 + nr)>>4, lrk = nr&15;
    {
      int d0 = qd, c = d0>>5, lg = (d0>>3)&3;
      *(u16x8*)(kO + (size_t)bh*65536 + ((size_t)(t16*2+c)*64 + lg*16 + lrk)*8) = o0;
    }
    {
      int d0 = qd+8, c = d0>>5, lg = (d0>>3)&3;
      *(u16x8*)(kO + (size_t)bh*65536 + ((size_t)(t16*2+c)*64 + lg*16 + lrk)*8) = o1;
    }
  }
  // V: transpose via LDS, then write fragment-major
  {
    u16x8 a0 = *(const u16x8*)(rowp + 2048 + h*64 + qd);
    u16x8 a1 = *(const u16x8*)(rowp + 2048 + h*64 + qd + 8);
#pragma unroll
    for (int jj=0;jj<8;jj++){ ldsv[qd+jj][nr] = a0[jj]; ldsv[qd+8+jj][nr] = a1[jj]; }
  }
  __syncthreads();
  {
    int d = t>>2, ns = (t&3)*16;
    int tt = d>>4, lrv = d&15;
    int m = (n0 + ns)>>5;
    int hf = (ns>>4)&1;
    u16* basep = vO + (size_t)bh*65536 + ((size_t)(m*4+tt)*64 + lrv)*8 + hf*4;
#pragma unroll
    for (int g=0; g<4; ++g){
      u16x4 wv4 = { ldsv[d][ns+g*4], ldsv[d][ns+g*4+1], ldsv[d][ns+g*4+2], ldsv[d][ns+g*4+3] };
      *(u16x4*)(basep + (size_t)g*128) = wv4;
    }
  }
}

// ---------------- flash attention: split-K x2, coalesced fragment loads, defer-max, exp2 ----------------
// grid (16 qgroups of 64 rows, 64 bh), block 512. Wave w: qtile = w>>1 (16 rows), kv-half = w&1 (512 kv).
// All K/V loads are lane-contiguous (1KB/instr) thanks to fragment-major layouts from repack.
__global__ __launch_bounds__(512) void attn_fwd(const u16* __restrict__ qO,
    const u16* __restrict__ kO, const u16* __restrict__ vO, u16* __restrict__ o)
{
  __shared__ __align__(16) float obuf[4][64][16];   // [pair][lane][tt*4+r] partial O (half 1)
  __shared__ __align__(16) float mlb[4][2][2][16];  // [pair][half][{m,l}][row]
  int bh = blockIdx.y, b = bh>>4, h = bh&15;
  int w = threadIdx.x>>6, lane = threadIdx.x&63;
  int pair = w>>1, half = w&1;
  int lr = lane&15, lg = lane>>4;
  int q0 = blockIdx.x*64 + pair*16;
  const u16* qp = qO + ((size_t)bh*1024 + q0 + lr)*64 + lg*8;
  bf16x8 qf0 = *(const bf16x8*)qp;
  bf16x8 qf1 = *(const bf16x8*)(qp + 32);
  const u16* kb = kO + (size_t)bh*65536 + (size_t)half*32768 + (size_t)lane*8;
  const u16* vb = vO + (size_t)bh*65536 + (size_t)half*32768 + (size_t)lane*8;
  f32x4 oacc[4] = {};
  float mrun = -3.0e38f, lrun = 0.f;
  for (int it=0; it<16; ++it){
    // K fragments: 2 kv16-tiles x 2 chunks, each 64 lanes x 16B contiguous
    const u16* kp = kb + (size_t)it*4096;
    bf16x8 k00 = *(const bf16x8*)(kp);
    bf16x8 k01 = *(const bf16x8*)(kp + 512);
    bf16x8 k10 = *(const bf16x8*)(kp + 1024);
    bf16x8 k11 = *(const bf16x8*)(kp + 1536);
    // S^T = K . Q^T : lane holds q=lr, kv = it*32 + {0,16} + lg*4 + r  (exp2 units)
    f32x4 s0 = {}, s1 = {};
    s0 = mfma16(k00, qf0, s0); s0 = mfma16(k01, qf1, s0);
    s1 = mfma16(k10, qf0, s1); s1 = mfma16(k11, qf1, s1);
    // V fragments (independent of softmax -> latency hidden under it)
    const u16* vp = vb + (size_t)it*2048;
    bf16x8 vv[4];
#pragma unroll
    for (int tt=0;tt<4;tt++) vv[tt] = *(const bf16x8*)(vp + tt*512);
    // per-q-row tile max
    float pm = fmaxf(fmaxf(fmaxf(s0[0],s0[1]),fmaxf(s0[2],s0[3])),
                     fmaxf(fmaxf(s1[0],s1[1]),fmaxf(s1[2],s1[3])));
    pm = fmaxf(pm, __shfl_xor(pm, 16));
    pm = fmaxf(pm, __shfl_xor(pm, 32));
    // defer-max: only rescale when the running max grew by > 8 (P bounded by 2^8)
    if (__any(pm > mrun + 8.f)){
      float mnew = fmaxf(mrun, pm);
      float alpha = fexp2(mrun - mnew);
      mrun = mnew;
      lrun *= alpha;
      float ar[4];
#pragma unroll
      for (int r=0;r<4;r++) ar[r] = __shfl(alpha, lg*4 + r);
#pragma unroll
      for (int tt=0;tt<4;tt++)
#pragma unroll
        for (int r=0;r<4;r++) oacc[tt][r] *= ar[r];
    }
    float p0[4], p1[4]; float ls = 0.f;
#pragma unroll
    for (int r=0;r<4;r++){ p0[r]=fexp2(s0[r]-mrun); p1[r]=fexp2(s1[r]-mrun); ls += p0[r]+p1[r]; }
    ls += __shfl_xor(ls, 16); ls += __shfl_xor(ls, 32);
    lrun += ls;
    bf16x4 pa0, pa1;
#pragma unroll
    for (int r=0;r<4;r++){ pa0[r] = (__bf16)p0[r]; pa1[r] = (__bf16)p1[r]; }
#pragma unroll
    for (int tt=0;tt<4;tt++){
      bf16x4* vh = (bf16x4*)&vv[tt];
      oacc[tt] = mfma16k16(pa0, vh[0], oacc[tt]);
      oacc[tt] = mfma16k16(pa1, vh[1], oacc[tt]);
    }
  }
  // ---- merge the two kv-halves via LDS ----
  if (lg==0){ mlb[pair][half][0][lr] = mrun; mlb[pair][half][1][lr] = lrun; }
  __syncthreads();
  f32x4 m0 = *(const f32x4*)&mlb[pair][0][0][lg*4];
  f32x4 l0 = *(const f32x4*)&mlb[pair][0][1][lg*4];
  f32x4 m1 = *(const f32x4*)&mlb[pair][1][0][lg*4];
  f32x4 l1 = *(const f32x4*)&mlb[pair][1][1][lg*4];
  f32x4 fh;
#pragma unroll
  for (int r=0;r<4;r++){
    float m = fmaxf(m0[r], m1[r]);
    float e0 = fexp2(m0[r]-m), e1 = fexp2(m1[r]-m);
    float li = 1.f/(l0[r]*e0 + l1[r]*e1);
    fh[r] = (half ? e1 : e0)*li;
  }
  if (half==1){
#pragma unroll
    for (int tt=0;tt<4;tt++){
      f32x4 t;
#pragma unroll
      for (int r=0;r<4;r++) t[r] = oacc[tt][r]*fh[r];
      *(f32x4*)&obuf[pair][lane][tt*4] = t;
    }
  }
  __syncthreads();
  if (half==0){
#pragma unroll
    for (int tt=0;tt<4;tt++){
      f32x4 p = *(const f32x4*)&obuf[pair][lane][tt*4];
#pragma unroll
      for (int r=0;r<4;r++){
        int row = (b<<10) + q0 + lg*4 + r;
        int col = h*64 + tt*16 + lr;
        o[(size_t)row*1024 + col] = f2b(oacc[tt][r]*fh[r] + p[r]);
      }
    }
  }
}

// ---------------- SwiGLU: hid = silu(x1)*x2, zero-padded to 2752 cols ----------------
__global__ __launch_bounds__(256) void swiglu_k(const u16* __restrict__ x12, u16* __restrict__ hid)
{
  int r = blockIdx.y;
  int c4 = blockIdx.x*256 + threadIdx.x;
  if (c4 >= 688) return;
  int cc = c4*4;
  const u16* rowp = x12 + (size_t)r*5504;
  u16x4 x1 = *(const u16x4*)(rowp + cc);
  u16x2 x2a = *(const u16x2*)(rowp + 2730 + cc);
  u16x2 x2b = *(const u16x2*)(rowp + 2730 + cc + 2);
  u16 x2v[4] = {x2a[0],x2a[1],x2b[0],x2b[1]};
  u16x4 o;
#pragma unroll
  for (int jj=0;jj<4;jj++){
    float a = b2f(x1[jj]);
    float g = silu_f(a)*b2f(x2v[jj]);
    o[jj] = (cc+jj < 2730) ? f2b(g) : (u16)0;
  }
  *(u16x4*)&hid[(size_t)r*2752 + cc] = o;
}

extern "C" void kernel_launch(void* const* d_in, const int* in_sizes, int n_in,
                              void* d_out, int out_size, void* d_ws, size_t ws_size,
                              hipStream_t stream)
{
  (void)in_sizes; (void)n_in; (void)out_size; (void)ws_size;
  const float* x    = (const float*)d_in[0];
  const float* c    = (const float*)d_in[1];
  const float* n1w  = (const float*)d_in[2];
  const float* cw   = (const float*)d_in[3];
  const float* cb   = (const float*)d_in[4];
  const float* qkvw = (const float*)d_in[5];
  const float* qkvb = (const float*)d_in[6];
  const float* qnw  = (const float*)d_in[7];
  const float* knw  = (const float*)d_in[8];
  const float* pw   = (const float*)d_in[9];
  const float* pb   = (const float*)d_in[10];
  const float* ew   = (const float*)d_in[11];
  const float* eb   = (const float*)d_in[12];
  const float* n2w  = (const float*)d_in[13];
  const float* w12w = (const float*)d_in[14];
  const float* w12b = (const float*)d_in[15];
  const float* w3w  = (const float*)d_in[16];
  const float* w3b  = (const float*)d_in[17];
  const float* adaw = (const float*)d_in[18];
  const float* adab = (const float*)d_in[19];
  float* out = (float*)d_out;
  char* ws = (char*)d_ws;
  auto U = [&](size_t off){ return (u16*)(ws + off); };
  auto F = [&](size_t off){ return (float*)(ws + off); };

  // weight conversions (bf16, zero-padded)
  convert_pad<<<dim3(1,1024), 256, 0, stream>>>(cw,   U(OFF_WC),   1024, 1024, 1024);
  convert_pad<<<dim3(1,3072), 256, 0, stream>>>(qkvw, U(OFF_WQKV), 3072, 1024, 1024);
  convert_pad<<<dim3(1,1024), 256, 0, stream>>>(pw,   U(OFF_WPROJ),1024, 1024, 1024);
  convert_pad<<<dim3(1,1024), 256, 0, stream>>>(ew,   U(OFF_WEXP), 1024, 1024, 1024);
  convert_pad<<<dim3(1,5504), 256, 0, stream>>>(w12w, U(OFF_WW12), 5460, 1024, 1024);
  convert_pad<<<dim3(3,1024), 256, 0, stream>>>(w3w,  U(OFF_WW3),  1024, 2730, 2752);

  ada_kernel<<<1536, 256, 0, stream>>>(c, adaw, adab, F(OFF_ADA));

  // attention branch
  rms_mod<<<4096, 256, 0, stream>>>(x, n1w, F(OFF_ADA), 0, U(OFF_H1));
  gemm_bt<0><<<dim3(8,32),  256, 0, stream>>>(U(OFF_H1), U(OFF_WC),   cb,   1024, 1024, 1024, U(OFF_HC),   nullptr, nullptr, 0, nullptr);
  gemm_bt<0><<<dim3(24,32), 256, 0, stream>>>(U(OFF_HC), U(OFF_WQKV), qkvb, 3072, 1024, 3072, U(OFF_QKVO), nullptr, nullptr, 0, nullptr);
  repack_qkv<<<dim3(16,64), 256, 0, stream>>>(U(OFF_QKVO), qnw, knw, U(OFF_Q), U(OFF_K), U(OFF_VT));
  attn_fwd<<<dim3(16,64), 512, 0, stream>>>(U(OFF_Q), U(OFF_K), U(OFF_VT), U(OFF_O));
  gemm_bt<0><<<dim3(8,32), 256, 0, stream>>>(U(OFF_O),  U(OFF_WPROJ), pb, 1024, 1024, 1024, U(OFF_PR), nullptr, nullptr, 0, nullptr);
  gemm_bt<1><<<dim3(8,32), 256, 0, stream>>>(U(OFF_PR), U(OFF_WEXP),  eb, 1024, 1024, 1024, nullptr, x, F(OFF_ADA), 2, F(OFF_X2));

  // FFN branch
  rms_mod<<<4096, 256, 0, stream>>>(F(OFF_X2), n2w, F(OFF_ADA), 3, U(OFF_H2));
  gemm_bt<0><<<dim3(43,32), 256, 0, stream>>>(U(OFF_H2), U(OFF_WW12), w12b, 5504, 1024, 5460, U(OFF_X12), nullptr, nullptr, 0, nullptr);
  swiglu_k<<<dim3(3,4096), 256, 0, stream>>>(U(OFF_X12), U(OFF_HID));
  gemm_bt<1><<<dim3(8,32), 256, 0, stream>>>(U(OFF_HID), U(OFF_WW3), w3b, 1024, 2752, 1024, nullptr, F(OFF_X2), F(OFF_ADA), 5, out);
}

// Round 5
// 385.539 us; speedup vs baseline: 1.3348x; 1.0144x over previous
//
#include <hip/hip_runtime.h>
#include <hip/hip_bf16.h>
#include <cstdint>
#include <cstddef>

typedef unsigned short u16;
typedef __bf16 bf16x8 __attribute__((ext_vector_type(8)));
typedef __bf16 bf16x4 __attribute__((ext_vector_type(4)));
typedef short   s16x4 __attribute__((ext_vector_type(4)));
typedef float    f32x4 __attribute__((ext_vector_type(4)));
typedef unsigned short u16x2 __attribute__((ext_vector_type(2)));
typedef unsigned short u16x4 __attribute__((ext_vector_type(4)));
typedef unsigned short u16x8 __attribute__((ext_vector_type(8)));

#define DEVI static __device__ __forceinline__

DEVI float b2f(u16 u){ union{unsigned i; float v;} x; x.i=((unsigned)u)<<16; return x.v; }
DEVI u16 f2b(float f){ union{float v; unsigned i;} x; x.v=f; unsigned r=x.i+0x7FFFu+((x.i>>16)&1u); return (u16)(r>>16); }
DEVI f32x4 mfma16(bf16x8 a, bf16x8 b, f32x4 c){ return __builtin_amdgcn_mfma_f32_16x16x32_bf16(a,b,c,0,0,0); }
DEVI f32x4 mfma16k16(bf16x4 a, bf16x4 b, f32x4 c){
#if __has_builtin(__builtin_amdgcn_mfma_f32_16x16x16_bf16)
  return __builtin_amdgcn_mfma_f32_16x16x16_bf16(a,b,c,0,0,0);
#elif __has_builtin(__builtin_amdgcn_mfma_f32_16x16x16bf16_1k)
  return __builtin_amdgcn_mfma_f32_16x16x16bf16_1k((s16x4)a,(s16x4)b,c,0,0,0);
#else
  asm volatile("v_mfma_f32_16x16x16_bf16 %0, %1, %2, %0" : "+v"(c) : "v"(a), "v"(b));
  return c;
#endif
}
DEVI float fexp2(float x){ return __builtin_amdgcn_exp2f(x); }
DEVI void gload16(const void* g, void* l){
  __builtin_amdgcn_global_load_lds((const __attribute__((address_space(1))) void*)g,
                                   (__attribute__((address_space(3))) void*)l, 16, 0, 0);
}
DEVI float silu_f(float x){ return x/(1.f+__expf(-x)); }

// ---------------- workspace layout (bytes) ----------------
static constexpr size_t OFF_WC   = 0;
static constexpr size_t OFF_WQKV = OFF_WC   + (size_t)1024*1024*2;
static constexpr size_t OFF_WPROJ= OFF_WQKV + (size_t)3072*1024*2;
static constexpr size_t OFF_WEXP = OFF_WPROJ+ (size_t)1024*1024*2;
static constexpr size_t OFF_WW12 = OFF_WEXP + (size_t)1024*1024*2;
static constexpr size_t OFF_WW3  = OFF_WW12 + (size_t)5632*1024*2;
static constexpr size_t OFF_ADA  = OFF_WW3  + (size_t)1024*2752*2;
static constexpr size_t OFF_X2   = OFF_ADA  + (size_t)4*6144*4;
static constexpr size_t OFF_P1   = OFF_X2   + (size_t)4096*1024*4;
static constexpr size_t OFF_H1   = OFF_P1;
static constexpr size_t OFF_HC   = OFF_H1   + (size_t)4096*1024*2;
static constexpr size_t OFF_QKVO = OFF_HC   + (size_t)4096*1024*2;
static constexpr size_t OFF_X12  = OFF_P1;                       // reuse: h1/hc/qkvO dead
static constexpr size_t OFF_P2   = OFF_P1   + (size_t)4096*5632*2;
static constexpr size_t OFF_Q    = OFF_P2;
static constexpr size_t OFF_K    = OFF_Q    + (size_t)64*1024*64*2;
static constexpr size_t OFF_VT   = OFF_K    + (size_t)64*1024*64*2;
static constexpr size_t OFF_O    = OFF_VT   + (size_t)64*1024*64*2;
static constexpr size_t OFF_PR   = OFF_O    + (size_t)4096*1024*2;
static constexpr size_t OFF_H2   = OFF_PR   + (size_t)4096*1024*2;
static constexpr size_t OFF_HID  = OFF_P2;                       // reuse: q/k/vt dead

// ---------------- fp32 -> bf16 weight conversion with zero padding ----------------
__global__ __launch_bounds__(256) void convert_pad(const float* __restrict__ src, u16* __restrict__ dst,
                                                   int R, int C, int Cpad)
{
  int r = blockIdx.y;
  int c0 = (blockIdx.x*256 + threadIdx.x)*4;
  if (c0 >= Cpad) return;
  u16x4 o;
#pragma unroll
  for (int j=0;j<4;j++){
    int cc = c0+j;
    float f = (r < R && cc < C) ? src[(size_t)r*C + cc] : 0.f;
    o[j] = f2b(f);
  }
  *(u16x4*)&dst[(size_t)r*Cpad + c0] = o;
}

// ---------------- adaLN: ada = silu(c) @ ada_w.T + ada_b  -> [4][6144] fp32 ----------------
__global__ __launch_bounds__(256) void ada_kernel(const float* __restrict__ c,
    const float* __restrict__ aw, const float* __restrict__ ab, float* __restrict__ ada)
{
  __shared__ float s[4][1024];
  int t = threadIdx.x;
#pragma unroll
  for (int i=0;i<16;i++){
    int idx = i*256 + t;
    float cv = c[idx];
    s[idx>>10][idx&1023] = cv/(1.f+__expf(-cv));
  }
  __syncthreads();
  int wid = t>>6, lane = t&63;
  int j = blockIdx.x*4 + wid;
  const f32x4* wp = (const f32x4*)(aw + (size_t)j*1024);
  float a0=0,a1=0,a2=0,a3=0;
#pragma unroll
  for (int i=0;i<4;i++){
    f32x4 wv = wp[i*64 + lane];
    int k0 = (i*64+lane)*4;
#pragma unroll
    for (int e=0;e<4;e++){
      float w = wv[e];
      a0 += w*s[0][k0+e]; a1 += w*s[1][k0+e]; a2 += w*s[2][k0+e]; a3 += w*s[3][k0+e];
    }
  }
#pragma unroll
  for (int mask=1; mask<64; mask<<=1){
    a0 += __shfl_xor(a0, mask); a1 += __shfl_xor(a1, mask);
    a2 += __shfl_xor(a2, mask); a3 += __shfl_xor(a3, mask);
  }
  if (lane==0){
    float bv = ab[j];
    ada[0*6144 + j] = a0 + bv;
    ada[1*6144 + j] = a1 + bv;
    ada[2*6144 + j] = a2 + bv;
    ada[3*6144 + j] = a3 + bv;
  }
}

// ---------------- fused RMSNorm + modulate -> bf16 ----------------
__global__ __launch_bounds__(256) void rms_mod(const float* __restrict__ x,
    const float* __restrict__ w, const float* __restrict__ ada, int chunkSh,
    u16* __restrict__ out)
{
  int row = blockIdx.x;
  int b = row>>10;
  int t = threadIdx.x;
  int wid = t>>6, lane = t&63;
  f32x4 v = *(const f32x4*)(x + (size_t)row*1024 + t*4);
  float ss = v[0]*v[0]+v[1]*v[1]+v[2]*v[2]+v[3]*v[3];
#pragma unroll
  for (int mask=1; mask<64; mask<<=1) ss += __shfl_xor(ss, mask);
  __shared__ float red[4];
  if (lane==0) red[wid]=ss;
  __syncthreads();
  float rinv = rsqrtf((red[0]+red[1]+red[2]+red[3])*(1.f/1024.f) + 1e-6f);
  int cc = t*4;
  const float* shp = ada + (size_t)b*6144 + (size_t)chunkSh*1024 + cc;
  u16x4 o;
#pragma unroll
  for (int jj=0;jj<4;jj++){
    float val = v[jj]*rinv*w[cc+jj];
    val = val*(1.f+shp[jj+1024]) + shp[jj];
    o[jj] = f2b(val);
  }
  *(u16x4*)&out[(size_t)row*1024 + cc] = o;
}

// ---------------- bf16 GEMM 128x128 (BK=32), source-side LDS swizzle ----------------
// EPI 0: store bf16 at outb, ld = N (padded). EPI 1: outf = xres + gate*(acc+bias), ld=1024.
template<int EPI>
__global__ __launch_bounds__(256,2) void gemm_bt(
    const u16* __restrict__ A, const u16* __restrict__ Bw, const float* __restrict__ bias,
    int N, int K, int nbias, u16* __restrict__ outb,
    const float* __restrict__ xres, const float* __restrict__ ada, int adaChunk,
    float* __restrict__ outf)
{
  __shared__ __align__(16) u16 As[128*32];
  __shared__ __align__(16) u16 Bs[128*32];
  int t = threadIdx.x;
  int wid = t>>6, lane = t&63;
  int lr = lane&15, lg = lane>>4;
  int bm = blockIdx.y, bn = blockIdx.x;
  // stage: thread t -> row t>>2 (and +64), LDS pos t&3, global chunk (t&3)^(row&3)
  int schunk = ((t&3) ^ ((t>>2)&3))*8;
  const u16* pA = A  + (size_t)(bm*128 + (t>>2))*K + schunk;
  const u16* pB = Bw + (size_t)(bn*128 + (t>>2))*K + schunk;
  u16* lA = As + t*8;
  u16* lB = Bs + t*8;
  int wr = (wid>>1)*64, wc = (wid&1)*64;
  int rp = (lg ^ (lr&3))*8;      // swizzled read position within a row
  f32x4 acc[4][4] = {};
  for (int kk=0; kk<K; kk+=32){
    gload16(pA, lA);
    gload16(pA + (size_t)64*K, lA + 64*32);
    gload16(pB, lB);
    gload16(pB + (size_t)64*K, lB + 64*32);
    pA += 32; pB += 32;
    __syncthreads();
    bf16x8 af[4], bfr[4];
#pragma unroll
    for (int m=0;m<4;m++) af[m]  = *(const bf16x8*)&As[(wr + m*16 + lr)*32 + rp];
#pragma unroll
    for (int n=0;n<4;n++) bfr[n] = *(const bf16x8*)&Bs[(wc + n*16 + lr)*32 + rp];
#pragma unroll
    for (int m=0;m<4;m++)
#pragma unroll
      for (int n=0;n<4;n++)
        acc[m][n] = mfma16(af[m], bfr[n], acc[m][n]);
    __syncthreads();
  }
#pragma unroll
  for (int n=0;n<4;n++){
    int col = bn*128 + wc + n*16 + lr;
    float bv = (col < nbias) ? bias[col] : 0.f;
#pragma unroll
    for (int m=0;m<4;m++){
      int row0 = bm*128 + wr + m*16 + lg*4;
#pragma unroll
      for (int r=0;r<4;r++){
        int row = row0 + r;
        float v = acc[m][n][r] + bv;
        if constexpr (EPI==0){
          outb[(size_t)row*N + col] = f2b(v);
        } else {
          int bb = row>>10;
          float g = ada[(size_t)bb*6144 + (size_t)adaChunk*1024 + col];
          outf[(size_t)row*1024 + col] = xres[(size_t)row*1024 + col] + g*v;
        }
      }
    }
  }
}

// ---------------- bf16 GEMM 256x256 (BK=64), 8 waves, 4-phase interleave, T2 swizzle ----------------
// C = A[M,K] * Bw[N,K]^T + bias, bf16 out with ld = N. Requires M%256==0, N%256==0, K%64==0.
__global__ __launch_bounds__(512,2) void gemm256(
    const u16* __restrict__ A, const u16* __restrict__ Bw, const float* __restrict__ bias,
    int N, int K, int nbias, u16* __restrict__ outb)
{
  __shared__ __align__(16) u16 lds[2][2][256*64];   // [buf][A/B][row*64 + pos*8]
  int t = threadIdx.x;
  int lane = t&63, w = t>>6;
  int wr = w>>2, wc = w&3;          // 2x4 wave grid
  int lr = lane&15, lg = lane>>4;
  int bm = blockIdx.y, bn = blockIdx.x;
  // staging: thread t -> group-row t>>3, LDS pos t&7, global chunk (t&7)^(row&7)
  int srow = t>>3;
  int schunk = ((t&7) ^ (srow&7))*8;
  const u16* pA = A  + (size_t)(bm*256 + srow)*K + schunk;
  const u16* pB = Bw + (size_t)(bn*256 + srow)*K + schunk;
  int ldst = t*8;                   // u16 offset within region (+ g*4096)
  f32x4 acc[8][4] = {};
  int NT = K>>6;
  // prologue: stage tile 0 -> buf 0
#pragma unroll
  for (int g=0; g<4; ++g){
    gload16(pA + (size_t)g*64*K, &lds[0][0][g*4096 + ldst]);
    gload16(pB + (size_t)g*64*K, &lds[0][1][g*4096 + ldst]);
  }
  __syncthreads();
  for (int kt=0; kt<NT; ++kt){
    int cur = kt&1;
    const u16* nA = pA + (size_t)(kt+1)*64;
    const u16* nB = pB + (size_t)(kt+1)*64;
    bool pre = (kt+1 < NT);
    bf16x8 af[4][2];
#pragma unroll
    for (int q=0; q<4; ++q){
      int rh = q>>1, ch = q&1;
      if (pre){
        gload16(nA + (size_t)q*64*K, &lds[cur^1][0][q*4096 + ldst]);
        gload16(nB + (size_t)q*64*K, &lds[cur^1][1][q*4096 + ldst]);
      }
      if (ch==0){
#pragma unroll
        for (int m2=0;m2<4;m2++){
          int R = wr*128 + rh*64 + m2*16 + lr;
#pragma unroll
          for (int kh=0;kh<2;kh++){
            int p = (kh*4+lg) ^ (lr&7);
            af[m2][kh] = *(const bf16x8*)&lds[cur][0][R*64 + p*8];
          }
        }
      }
      bf16x8 bf[2][2];
#pragma unroll
      for (int n2=0;n2<2;n2++){
        int S = wc*64 + ch*32 + n2*16 + lr;
#pragma unroll
        for (int kh=0;kh<2;kh++){
          int p = (kh*4+lg) ^ (lr&7);
          bf[n2][kh] = *(const bf16x8*)&lds[cur][1][S*64 + p*8];
        }
      }
      __builtin_amdgcn_s_setprio(1);
#pragma unroll
      for (int m2=0;m2<4;m2++)
#pragma unroll
        for (int n2=0;n2<2;n2++)
#pragma unroll
          for (int kh=0;kh<2;kh++)
            acc[rh*4+m2][ch*2+n2] = mfma16(af[m2][kh], bf[n2][kh], acc[rh*4+m2][ch*2+n2]);
      __builtin_amdgcn_s_setprio(0);
      if (q < 3) __builtin_amdgcn_s_barrier();
    }
    __syncthreads();   // drain stage loads for tile kt+1 + rendezvous
  }
#pragma unroll
  for (int n=0;n<4;n++){
    int col = bn*256 + wc*64 + n*16 + lr;
    float bv = (col < nbias) ? bias[col] : 0.f;
#pragma unroll
    for (int m=0;m<8;m++){
      int row0 = bm*256 + wr*128 + m*16 + lg*4;
#pragma unroll
      for (int r=0;r<4;r++)
        outb[(size_t)(row0+r)*N + col] = f2b(acc[m][n][r] + bv);
    }
  }
}

// ---------------- qkv repack: rms-norm q,k per head, fragment-major K/V for attention ----------------
// q pre-scaled by (1/8)*log2(e) so attention softmax runs in exp2 domain.
__global__ __launch_bounds__(256) void repack_qkv(const u16* __restrict__ qkvO,
    const float* __restrict__ qnw, const float* __restrict__ knw,
    u16* __restrict__ qO, u16* __restrict__ kO, u16* __restrict__ vO)
{
  __shared__ u16 ldsv[64][64];
  int bh = blockIdx.y, b = bh>>4, h = bh&15;
  int n0 = blockIdx.x*64;
  int t = threadIdx.x;
  int nr = t>>2, qd = (t&3)*16;
  const u16* rowp = qkvO + (size_t)(b*1024 + n0 + nr)*3072;
  // Q: rms-norm * qn_w * (1/8)*log2e  (standard [bh][n][d] layout)
  {
    u16x8 a0 = *(const u16x8*)(rowp + h*64 + qd);
    u16x8 a1 = *(const u16x8*)(rowp + h*64 + qd + 8);
    float f[16]; float ss=0;
#pragma unroll
    for (int jj=0;jj<8;jj++){ f[jj]=b2f(a0[jj]); f[8+jj]=b2f(a1[jj]); }
#pragma unroll
    for (int jj=0;jj<16;jj++) ss += f[jj]*f[jj];
    ss += __shfl_xor(ss,1); ss += __shfl_xor(ss,2);
    float rinv = rsqrtf(ss*(1.f/64.f)+1e-6f)*0.125f*1.44269504089f;
    u16x8 o0,o1;
#pragma unroll
    for (int jj=0;jj<8;jj++){ o0[jj]=f2b(f[jj]*rinv*qnw[qd+jj]); o1[jj]=f2b(f[8+jj]*rinv*qnw[qd+8+jj]); }
    u16* dst = qO + ((size_t)bh*1024 + n0 + nr)*64 + qd;
    *(u16x8*)dst = o0; *(u16x8*)(dst+8) = o1;
  }
  // K: rms-norm * kn_w -> fragment-major
  {
    u16x8 a0 = *(const u16x8*)(rowp + 1024 + h*64 + qd);
    u16x8 a1 = *(const u16x8*)(rowp + 1024 + h*64 + qd + 8);
    float f[16]; float ss=0;
#pragma unroll
    for (int jj=0;jj<8;jj++){ f[jj]=b2f(a0[jj]); f[8+jj]=b2f(a1[jj]); }
#pragma unroll
    for (int jj=0;jj<16;jj++) ss += f[jj]*f[jj];
    ss += __shfl_xor(ss,1); ss += __shfl_xor(ss,2);
    float rinv = rsqrtf(ss*(1.f/64.f)+1e-6f);
    u16x8 o0,o1;
#pragma unroll
    for (int jj=0;jj<8;jj++){ o0[jj]=f2b(f[jj]*rinv*knw[qd+jj]); o1[jj]=f2b(f[8+jj]*rinv*knw[qd+8+jj]); }
    int t16 = (n0 + nr)>>4, lrk = nr&15;
    {
      int d0 = qd, c = d0>>5, lg = (d0>>3)&3;
      *(u16x8*)(kO + (size_t)bh*65536 + ((size_t)(t16*2+c)*64 + lg*16 + lrk)*8) = o0;
    }
    {
      int d0 = qd+8, c = d0>>5, lg = (d0>>3)&3;
      *(u16x8*)(kO + (size_t)bh*65536 + ((size_t)(t16*2+c)*64 + lg*16 + lrk)*8) = o1;
    }
  }
  // V: transpose via LDS, then write fragment-major
  {
    u16x8 a0 = *(const u16x8*)(rowp + 2048 + h*64 + qd);
    u16x8 a1 = *(const u16x8*)(rowp + 2048 + h*64 + qd + 8);
#pragma unroll
    for (int jj=0;jj<8;jj++){ ldsv[qd+jj][nr] = a0[jj]; ldsv[qd+8+jj][nr] = a1[jj]; }
  }
  __syncthreads();
  {
    int d = t>>2, ns = (t&3)*16;
    int tt = d>>4, lrv = d&15;
    int m = (n0 + ns)>>5;
    int hf = (ns>>4)&1;
    u16* basep = vO + (size_t)bh*65536 + ((size_t)(m*4+tt)*64 + lrv)*8 + hf*4;
#pragma unroll
    for (int g=0; g<4; ++g){
      u16x4 wv4 = { ldsv[d][ns+g*4], ldsv[d][ns+g*4+1], ldsv[d][ns+g*4+2], ldsv[d][ns+g*4+3] };
      *(u16x4*)(basep + (size_t)g*128) = wv4;
    }
  }
}

// ---------------- flash attention: split-K x2, coalesced fragment loads, defer-max, exp2 ----------------
__global__ __launch_bounds__(512) void attn_fwd(const u16* __restrict__ qO,
    const u16* __restrict__ kO, const u16* __restrict__ vO, u16* __restrict__ o)
{
  __shared__ __align__(16) float obuf[4][64][16];   // [pair][lane][tt*4+r] partial O (half 1)
  __shared__ __align__(16) float mlb[4][2][2][16];  // [pair][half][{m,l}][row]
  int bh = blockIdx.y, b = bh>>4, h = bh&15;
  int w = threadIdx.x>>6, lane = threadIdx.x&63;
  int pair = w>>1, half = w&1;
  int lr = lane&15, lg = lane>>4;
  int q0 = blockIdx.x*64 + pair*16;
  const u16* qp = qO + ((size_t)bh*1024 + q0 + lr)*64 + lg*8;
  bf16x8 qf0 = *(const bf16x8*)qp;
  bf16x8 qf1 = *(const bf16x8*)(qp + 32);
  const u16* kb = kO + (size_t)bh*65536 + (size_t)half*32768 + (size_t)lane*8;
  const u16* vb = vO + (size_t)bh*65536 + (size_t)half*32768 + (size_t)lane*8;
  f32x4 oacc[4] = {};
  float mrun = -3.0e38f, lrun = 0.f;
  for (int it=0; it<16; ++it){
    const u16* kp = kb + (size_t)it*4096;
    bf16x8 k00 = *(const bf16x8*)(kp);
    bf16x8 k01 = *(const bf16x8*)(kp + 512);
    bf16x8 k10 = *(const bf16x8*)(kp + 1024);
    bf16x8 k11 = *(const bf16x8*)(kp + 1536);
    f32x4 s0 = {}, s1 = {};
    s0 = mfma16(k00, qf0, s0); s0 = mfma16(k01, qf1, s0);
    s1 = mfma16(k10, qf0, s1); s1 = mfma16(k11, qf1, s1);
    const u16* vp = vb + (size_t)it*2048;
    bf16x8 vv[4];
#pragma unroll
    for (int tt=0;tt<4;tt++) vv[tt] = *(const bf16x8*)(vp + tt*512);
    float pm = fmaxf(fmaxf(fmaxf(s0[0],s0[1]),fmaxf(s0[2],s0[3])),
                     fmaxf(fmaxf(s1[0],s1[1]),fmaxf(s1[2],s1[3])));
    pm = fmaxf(pm, __shfl_xor(pm, 16));
    pm = fmaxf(pm, __shfl_xor(pm, 32));
    if (__any(pm > mrun + 8.f)){
      float mnew = fmaxf(mrun, pm);
      float alpha = fexp2(mrun - mnew);
      mrun = mnew;
      lrun *= alpha;
      float ar[4];
#pragma unroll
      for (int r=0;r<4;r++) ar[r] = __shfl(alpha, lg*4 + r);
#pragma unroll
      for (int tt=0;tt<4;tt++)
#pragma unroll
        for (int r=0;r<4;r++) oacc[tt][r] *= ar[r];
    }
    float p0[4], p1[4]; float ls = 0.f;
#pragma unroll
    for (int r=0;r<4;r++){ p0[r]=fexp2(s0[r]-mrun); p1[r]=fexp2(s1[r]-mrun); ls += p0[r]+p1[r]; }
    ls += __shfl_xor(ls, 16); ls += __shfl_xor(ls, 32);
    lrun += ls;
    bf16x4 pa0, pa1;
#pragma unroll
    for (int r=0;r<4;r++){ pa0[r] = (__bf16)p0[r]; pa1[r] = (__bf16)p1[r]; }
#pragma unroll
    for (int tt=0;tt<4;tt++){
      bf16x4* vh = (bf16x4*)&vv[tt];
      oacc[tt] = mfma16k16(pa0, vh[0], oacc[tt]);
      oacc[tt] = mfma16k16(pa1, vh[1], oacc[tt]);
    }
  }
  if (lg==0){ mlb[pair][half][0][lr] = mrun; mlb[pair][half][1][lr] = lrun; }
  __syncthreads();
  f32x4 m0 = *(const f32x4*)&mlb[pair][0][0][lg*4];
  f32x4 l0 = *(const f32x4*)&mlb[pair][0][1][lg*4];
  f32x4 m1 = *(const f32x4*)&mlb[pair][1][0][lg*4];
  f32x4 l1 = *(const f32x4*)&mlb[pair][1][1][lg*4];
  f32x4 fh;
#pragma unroll
  for (int r=0;r<4;r++){
    float m = fmaxf(m0[r], m1[r]);
    float e0 = fexp2(m0[r]-m), e1 = fexp2(m1[r]-m);
    float li = 1.f/(l0[r]*e0 + l1[r]*e1);
    fh[r] = (half ? e1 : e0)*li;
  }
  if (half==1){
#pragma unroll
    for (int tt=0;tt<4;tt++){
      f32x4 tv;
#pragma unroll
      for (int r=0;r<4;r++) tv[r] = oacc[tt][r]*fh[r];
      *(f32x4*)&obuf[pair][lane][tt*4] = tv;
    }
  }
  __syncthreads();
  if (half==0){
#pragma unroll
    for (int tt=0;tt<4;tt++){
      f32x4 p = *(const f32x4*)&obuf[pair][lane][tt*4];
#pragma unroll
      for (int r=0;r<4;r++){
        int row = (b<<10) + q0 + lg*4 + r;
        int col = h*64 + tt*16 + lr;
        o[(size_t)row*1024 + col] = f2b(oacc[tt][r]*fh[r] + p[r]);
      }
    }
  }
}

// ---------------- SwiGLU: hid = silu(x1)*x2, zero-padded to 2752 cols ----------------
__global__ __launch_bounds__(256) void swiglu_k(const u16* __restrict__ x12, u16* __restrict__ hid)
{
  int r = blockIdx.y;
  int c4 = blockIdx.x*256 + threadIdx.x;
  if (c4 >= 688) return;
  int cc = c4*4;
  const u16* rowp = x12 + (size_t)r*5632;
  u16x4 x1 = *(const u16x4*)(rowp + cc);
  u16x2 x2a = *(const u16x2*)(rowp + 2730 + cc);
  u16x2 x2b = *(const u16x2*)(rowp + 2730 + cc + 2);
  u16 x2v[4] = {x2a[0],x2a[1],x2b[0],x2b[1]};
  u16x4 o;
#pragma unroll
  for (int jj=0;jj<4;jj++){
    float a = b2f(x1[jj]);
    float g = silu_f(a)*b2f(x2v[jj]);
    o[jj] = (cc+jj < 2730) ? f2b(g) : (u16)0;
  }
  *(u16x4*)&hid[(size_t)r*2752 + cc] = o;
}

extern "C" void kernel_launch(void* const* d_in, const int* in_sizes, int n_in,
                              void* d_out, int out_size, void* d_ws, size_t ws_size,
                              hipStream_t stream)
{
  (void)in_sizes; (void)n_in; (void)out_size; (void)ws_size;
  const float* x    = (const float*)d_in[0];
  const float* c    = (const float*)d_in[1];
  const float* n1w  = (const float*)d_in[2];
  const float* cw   = (const float*)d_in[3];
  const float* cb   = (const float*)d_in[4];
  const float* qkvw = (const float*)d_in[5];
  const float* qkvb = (const float*)d_in[6];
  const float* qnw  = (const float*)d_in[7];
  const float* knw  = (const float*)d_in[8];
  const float* pw   = (const float*)d_in[9];
  const float* pb   = (const float*)d_in[10];
  const float* ew   = (const float*)d_in[11];
  const float* eb   = (const float*)d_in[12];
  const float* n2w  = (const float*)d_in[13];
  const float* w12w = (const float*)d_in[14];
  const float* w12b = (const float*)d_in[15];
  const float* w3w  = (const float*)d_in[16];
  const float* w3b  = (const float*)d_in[17];
  const float* adaw = (const float*)d_in[18];
  const float* adab = (const float*)d_in[19];
  float* out = (float*)d_out;
  char* ws = (char*)d_ws;
  auto U = [&](size_t off){ return (u16*)(ws + off); };
  auto F = [&](size_t off){ return (float*)(ws + off); };

  // weight conversions (bf16, zero-padded)
  convert_pad<<<dim3(1,1024), 256, 0, stream>>>(cw,   U(OFF_WC),   1024, 1024, 1024);
  convert_pad<<<dim3(1,3072), 256, 0, stream>>>(qkvw, U(OFF_WQKV), 3072, 1024, 1024);
  convert_pad<<<dim3(1,1024), 256, 0, stream>>>(pw,   U(OFF_WPROJ),1024, 1024, 1024);
  convert_pad<<<dim3(1,1024), 256, 0, stream>>>(ew,   U(OFF_WEXP), 1024, 1024, 1024);
  convert_pad<<<dim3(1,5632), 256, 0, stream>>>(w12w, U(OFF_WW12), 5460, 1024, 1024);
  convert_pad<<<dim3(3,1024), 256, 0, stream>>>(w3w,  U(OFF_WW3),  1024, 2730, 2752);

  ada_kernel<<<1536, 256, 0, stream>>>(c, adaw, adab, F(OFF_ADA));

  // attention branch
  rms_mod<<<4096, 256, 0, stream>>>(x, n1w, F(OFF_ADA), 0, U(OFF_H1));
  gemm_bt<0><<<dim3(8,32),  256, 0, stream>>>(U(OFF_H1), U(OFF_WC),   cb,   1024, 1024, 1024, U(OFF_HC),   nullptr, nullptr, 0, nullptr);
  gemm256<<<dim3(12,16), 512, 0, stream>>>(U(OFF_HC), U(OFF_WQKV), qkvb, 3072, 1024, 3072, U(OFF_QKVO));
  repack_qkv<<<dim3(16,64), 256, 0, stream>>>(U(OFF_QKVO), qnw, knw, U(OFF_Q), U(OFF_K), U(OFF_VT));
  attn_fwd<<<dim3(16,64), 512, 0, stream>>>(U(OFF_Q), U(OFF_K), U(OFF_VT), U(OFF_O));
  gemm_bt<0><<<dim3(8,32), 256, 0, stream>>>(U(OFF_O),  U(OFF_WPROJ), pb, 1024, 1024, 1024, U(OFF_PR), nullptr, nullptr, 0, nullptr);
  gemm_bt<1><<<dim3(8,32), 256, 0, stream>>>(U(OFF_PR), U(OFF_WEXP),  eb, 1024, 1024, 1024, nullptr, x, F(OFF_ADA), 2, F(OFF_X2));

  // FFN branch
  rms_mod<<<4096, 256, 0, stream>>>(F(OFF_X2), n2w, F(OFF_ADA), 3, U(OFF_H2));
  gemm256<<<dim3(22,16), 512, 0, stream>>>(U(OFF_H2), U(OFF_WW12), w12b, 5632, 1024, 5460, U(OFF_X12));
  swiglu_k<<<dim3(3,4096), 256, 0, stream>>>(U(OFF_X12), U(OFF_HID));
  gemm_bt<1><<<dim3(8,32), 256, 0, stream>>>(U(OFF_HID), U(OFF_WW3), w3b, 1024, 2752, 1024, nullptr, F(OFF_X2), F(OFF_ADA), 5, out);
}

// Round 6
// 354.713 us; speedup vs baseline: 1.4508x; 1.0869x over previous
//
#include <hip/hip_runtime.h>
#include <hip/hip_bf16.h>
#include <cstdint>
#include <cstddef>

typedef unsigned short u16;
typedef __bf16 bf16x8 __attribute__((ext_vector_type(8)));
typedef __bf16 bf16x4 __attribute__((ext_vector_type(4)));
typedef short   s16x4 __attribute__((ext_vector_type(4)));
typedef float    f32x4 __attribute__((ext_vector_type(4)));
typedef unsigned short u16x2 __attribute__((ext_vector_type(2)));
typedef unsigned short u16x4 __attribute__((ext_vector_type(4)));
typedef unsigned short u16x8 __attribute__((ext_vector_type(8)));

#define DEVI static __device__ __forceinline__

DEVI float b2f(u16 u){ union{unsigned i; float v;} x; x.i=((unsigned)u)<<16; return x.v; }
DEVI u16 f2b(float f){ union{float v; unsigned i;} x; x.v=f; unsigned r=x.i+0x7FFFu+((x.i>>16)&1u); return (u16)(r>>16); }
DEVI f32x4 mfma16(bf16x8 a, bf16x8 b, f32x4 c){ return __builtin_amdgcn_mfma_f32_16x16x32_bf16(a,b,c,0,0,0); }
DEVI f32x4 mfma16k16(bf16x4 a, bf16x4 b, f32x4 c){
#if __has_builtin(__builtin_amdgcn_mfma_f32_16x16x16_bf16)
  return __builtin_amdgcn_mfma_f32_16x16x16_bf16(a,b,c,0,0,0);
#elif __has_builtin(__builtin_amdgcn_mfma_f32_16x16x16bf16_1k)
  return __builtin_amdgcn_mfma_f32_16x16x16bf16_1k((s16x4)a,(s16x4)b,c,0,0,0);
#else
  asm volatile("v_mfma_f32_16x16x16_bf16 %0, %1, %2, %0" : "+v"(c) : "v"(a), "v"(b));
  return c;
#endif
}
DEVI float fexp2(float x){ return __builtin_amdgcn_exp2f(x); }
DEVI void gload16(const void* g, void* l){
  __builtin_amdgcn_global_load_lds((const __attribute__((address_space(1))) void*)g,
                                   (__attribute__((address_space(3))) void*)l, 16, 0, 0);
}
DEVI float silu_f(float x){ return x/(1.f+__expf(-x)); }

// ---------------- workspace layout (bytes) ----------------
static constexpr size_t OFF_WC   = 0;
static constexpr size_t OFF_WQKV = OFF_WC   + (size_t)1024*1024*2;
static constexpr size_t OFF_WPROJ= OFF_WQKV + (size_t)3072*1024*2;
static constexpr size_t OFF_WEXP = OFF_WPROJ+ (size_t)1024*1024*2;
static constexpr size_t OFF_WW12 = OFF_WEXP + (size_t)1024*1024*2;
static constexpr size_t OFF_WW3  = OFF_WW12 + (size_t)5632*1024*2;
static constexpr size_t OFF_ADA  = OFF_WW3  + (size_t)1024*2752*2;
static constexpr size_t OFF_X2   = OFF_ADA  + (size_t)4*6144*4;
static constexpr size_t OFF_P1   = OFF_X2   + (size_t)4096*1024*4;
static constexpr size_t OFF_H1   = OFF_P1;
static constexpr size_t OFF_HC   = OFF_H1   + (size_t)4096*1024*2;
static constexpr size_t OFF_QKVO = OFF_HC   + (size_t)4096*1024*2;
static constexpr size_t OFF_X12  = OFF_P1;                       // reuse: h1/hc/qkvO dead
static constexpr size_t OFF_P2   = OFF_P1   + (size_t)4096*5632*2;
static constexpr size_t OFF_Q    = OFF_P2;
static constexpr size_t OFF_K    = OFF_Q    + (size_t)64*1024*64*2;
static constexpr size_t OFF_VT   = OFF_K    + (size_t)64*1024*64*2;
static constexpr size_t OFF_O    = OFF_VT   + (size_t)64*1024*64*2;
static constexpr size_t OFF_PR   = OFF_O    + (size_t)4096*1024*2;
static constexpr size_t OFF_H2   = OFF_PR   + (size_t)4096*1024*2;
static constexpr size_t OFF_HID  = OFF_P2;                       // reuse: q/k/vt dead

// ---------------- fp32 -> bf16 weight conversion with zero padding ----------------
__global__ __launch_bounds__(256) void convert_pad(const float* __restrict__ src, u16* __restrict__ dst,
                                                   int R, int C, int Cpad)
{
  int r = blockIdx.y;
  int c0 = (blockIdx.x*256 + threadIdx.x)*4;
  if (c0 >= Cpad) return;
  u16x4 o;
#pragma unroll
  for (int j=0;j<4;j++){
    int cc = c0+j;
    float f = (r < R && cc < C) ? src[(size_t)r*C + cc] : 0.f;
    o[j] = f2b(f);
  }
  *(u16x4*)&dst[(size_t)r*Cpad + c0] = o;
}

// ---------------- adaLN: ada = silu(c) @ ada_w.T + ada_b  -> [4][6144] fp32 ----------------
__global__ __launch_bounds__(256) void ada_kernel(const float* __restrict__ c,
    const float* __restrict__ aw, const float* __restrict__ ab, float* __restrict__ ada)
{
  __shared__ float s[4][1024];
  int t = threadIdx.x;
#pragma unroll
  for (int i=0;i<16;i++){
    int idx = i*256 + t;
    float cv = c[idx];
    s[idx>>10][idx&1023] = cv/(1.f+__expf(-cv));
  }
  __syncthreads();
  int wid = t>>6, lane = t&63;
  int j = blockIdx.x*4 + wid;
  const f32x4* wp = (const f32x4*)(aw + (size_t)j*1024);
  float a0=0,a1=0,a2=0,a3=0;
#pragma unroll
  for (int i=0;i<4;i++){
    f32x4 wv = wp[i*64 + lane];
    int k0 = (i*64+lane)*4;
#pragma unroll
    for (int e=0;e<4;e++){
      float w = wv[e];
      a0 += w*s[0][k0+e]; a1 += w*s[1][k0+e]; a2 += w*s[2][k0+e]; a3 += w*s[3][k0+e];
    }
  }
#pragma unroll
  for (int mask=1; mask<64; mask<<=1){
    a0 += __shfl_xor(a0, mask); a1 += __shfl_xor(a1, mask);
    a2 += __shfl_xor(a2, mask); a3 += __shfl_xor(a3, mask);
  }
  if (lane==0){
    float bv = ab[j];
    ada[0*6144 + j] = a0 + bv;
    ada[1*6144 + j] = a1 + bv;
    ada[2*6144 + j] = a2 + bv;
    ada[3*6144 + j] = a3 + bv;
  }
}

// ---------------- fused RMSNorm + modulate -> bf16 ----------------
__global__ __launch_bounds__(256) void rms_mod(const float* __restrict__ x,
    const float* __restrict__ w, const float* __restrict__ ada, int chunkSh,
    u16* __restrict__ out)
{
  int row = blockIdx.x;
  int b = row>>10;
  int t = threadIdx.x;
  int wid = t>>6, lane = t&63;
  f32x4 v = *(const f32x4*)(x + (size_t)row*1024 + t*4);
  float ss = v[0]*v[0]+v[1]*v[1]+v[2]*v[2]+v[3]*v[3];
#pragma unroll
  for (int mask=1; mask<64; mask<<=1) ss += __shfl_xor(ss, mask);
  __shared__ float red[4];
  if (lane==0) red[wid]=ss;
  __syncthreads();
  float rinv = rsqrtf((red[0]+red[1]+red[2]+red[3])*(1.f/1024.f) + 1e-6f);
  int cc = t*4;
  const float* shp = ada + (size_t)b*6144 + (size_t)chunkSh*1024 + cc;
  u16x4 o;
#pragma unroll
  for (int jj=0;jj<4;jj++){
    float val = v[jj]*rinv*w[cc+jj];
    val = val*(1.f+shp[jj+1024]) + shp[jj];
    o[jj] = f2b(val);
  }
  *(u16x4*)&out[(size_t)row*1024 + cc] = o;
}

// ---------------- bf16 GEMM 128x128 (BK=32), source-side LDS swizzle ----------------
template<int EPI>
__global__ __launch_bounds__(256,2) void gemm_bt(
    const u16* __restrict__ A, const u16* __restrict__ Bw, const float* __restrict__ bias,
    int N, int K, int nbias, u16* __restrict__ outb,
    const float* __restrict__ xres, const float* __restrict__ ada, int adaChunk,
    float* __restrict__ outf)
{
  __shared__ __align__(16) u16 As[128*32];
  __shared__ __align__(16) u16 Bs[128*32];
  int t = threadIdx.x;
  int wid = t>>6, lane = t&63;
  int lr = lane&15, lg = lane>>4;
  int bm = blockIdx.y, bn = blockIdx.x;
  int schunk = ((t&3) ^ ((t>>2)&3))*8;
  const u16* pA = A  + (size_t)(bm*128 + (t>>2))*K + schunk;
  const u16* pB = Bw + (size_t)(bn*128 + (t>>2))*K + schunk;
  u16* lA = As + t*8;
  u16* lB = Bs + t*8;
  int wr = (wid>>1)*64, wc = (wid&1)*64;
  int rp = (lg ^ (lr&3))*8;
  f32x4 acc[4][4] = {};
  for (int kk=0; kk<K; kk+=32){
    gload16(pA, lA);
    gload16(pA + (size_t)64*K, lA + 64*32);
    gload16(pB, lB);
    gload16(pB + (size_t)64*K, lB + 64*32);
    pA += 32; pB += 32;
    __syncthreads();
    bf16x8 af[4], bfr[4];
#pragma unroll
    for (int m=0;m<4;m++) af[m]  = *(const bf16x8*)&As[(wr + m*16 + lr)*32 + rp];
#pragma unroll
    for (int n=0;n<4;n++) bfr[n] = *(const bf16x8*)&Bs[(wc + n*16 + lr)*32 + rp];
#pragma unroll
    for (int m=0;m<4;m++)
#pragma unroll
      for (int n=0;n<4;n++)
        acc[m][n] = mfma16(af[m], bfr[n], acc[m][n]);
    __syncthreads();
  }
#pragma unroll
  for (int n=0;n<4;n++){
    int col = bn*128 + wc + n*16 + lr;
    float bv = (col < nbias) ? bias[col] : 0.f;
#pragma unroll
    for (int m=0;m<4;m++){
      int row0 = bm*128 + wr + m*16 + lg*4;
#pragma unroll
      for (int r=0;r<4;r++){
        int row = row0 + r;
        float v = acc[m][n][r] + bv;
        if constexpr (EPI==0){
          outb[(size_t)row*N + col] = f2b(v);
        } else {
          int bb = row>>10;
          float g = ada[(size_t)bb*6144 + (size_t)adaChunk*1024 + col];
          outf[(size_t)row*1024 + col] = xres[(size_t)row*1024 + col] + g*v;
        }
      }
    }
  }
}

// ---------------- bf16 GEMM BMx256 (BK=32), ring-4 LDS, counted-vmcnt deep pipeline ----------------
// Loads for tile t+2 issued at top of tile t; end-of-tile waits vmcnt(NLOAD) (never 0 in main loop).
// LDS swizzle: chunk' = chunk ^ ((row>>1)&3)  (2 lanes/bank on ds_read_b128 = free).
template<int BM, int EPI>
__global__ __launch_bounds__(512) void gemm_dp(
    const u16* __restrict__ A, const u16* __restrict__ Bw, const float* __restrict__ bias,
    int N, int K, int nbias, u16* __restrict__ outb,
    const float* __restrict__ xres, const float* __restrict__ ada, int adaChunk,
    float* __restrict__ outf)
{
  constexpr int AU = BM*32;            // A region size (u16)
  constexpr int RU = AU + 8192;        // ring unit size (u16): A + B(256x32)
  constexpr int WRB = (BM==256)?128:64;
  constexpr int MF  = WRB/16;          // 8 or 4 M-fragments per wave
  __shared__ __align__(16) u16 lds[4*RU];
  int t = threadIdx.x;
  int lane = t&63, w = t>>6;
  int wr = w>>2, wc = w&3;             // 2 x 4 wave grid
  int lr = lane&15, lg = lane>>4;
  int bm = blockIdx.y, bn = blockIdx.x;
  int arow = t>>2;
  int schunk = ((t&3) ^ ((t>>3)&3))*8; // pre-swizzled global source chunk
  const u16* pA = A  + (size_t)(bm*BM  + arow)*K + schunk;
  const u16* pB = Bw + (size_t)(bn*256 + arow)*K + schunk;
  int ldst = t*8;
  int rsw  = (lg ^ ((lr>>1)&3))*8;     // swizzled read position
  int aoff = (wr*WRB + lr)*32 + rsw;
  int boff = AU + (wc*64 + lr)*32 + rsw;
  f32x4 acc[MF][4] = {};
  int NT = K>>5;

  auto stage = [&](int kt, int rg){
    const u16* sa = pA + (size_t)kt*32;
    const u16* sb = pB + (size_t)kt*32;
    u16* dst = &lds[rg*RU];
    gload16(sa, dst + ldst);
    if constexpr (BM==256) gload16(sa + (size_t)128*K, dst + 4096 + ldst);
    gload16(sb, dst + AU + ldst);
    gload16(sb + (size_t)128*K, dst + AU + 4096 + ldst);
  };

  stage(0, 0);
  stage(1, 1);
  if constexpr (BM==256) asm volatile("s_waitcnt vmcnt(4)" ::: "memory");
  else                   asm volatile("s_waitcnt vmcnt(3)" ::: "memory");
  __builtin_amdgcn_s_barrier();
  __builtin_amdgcn_sched_barrier(0);

  for (int kt=0; kt<NT; ++kt){
    const u16* lb = &lds[(kt&3)*RU];
    if (kt+2 < NT) stage(kt+2, (kt+2)&3);
    bf16x8 bfr[4];
#pragma unroll
    for (int nf=0;nf<4;nf++) bfr[nf] = *(const bf16x8*)&lb[boff + nf*512];
    bf16x8 af[4];
#pragma unroll
    for (int mf=0;mf<4;mf++) af[mf] = *(const bf16x8*)&lb[aoff + mf*512];
    __builtin_amdgcn_s_setprio(1);
#pragma unroll
    for (int mf=0;mf<4;mf++)
#pragma unroll
      for (int nf=0;nf<4;nf++)
        acc[mf][nf] = mfma16(af[mf], bfr[nf], acc[mf][nf]);
    __builtin_amdgcn_s_setprio(0);
    if constexpr (BM==256){
      bf16x8 af2[4];
#pragma unroll
      for (int mf=0;mf<4;mf++) af2[mf] = *(const bf16x8*)&lb[aoff + (mf+4)*512];
      __builtin_amdgcn_s_setprio(1);
#pragma unroll
      for (int mf=0;mf<4;mf++)
#pragma unroll
        for (int nf=0;nf<4;nf++)
          acc[mf+4][nf] = mfma16(af2[mf], bfr[nf], acc[mf+4][nf]);
      __builtin_amdgcn_s_setprio(0);
    }
    if (kt+2 < NT){
      if constexpr (BM==256) asm volatile("s_waitcnt vmcnt(4)" ::: "memory");
      else                   asm volatile("s_waitcnt vmcnt(3)" ::: "memory");
    } else if (kt+1 < NT){
      asm volatile("s_waitcnt vmcnt(0)" ::: "memory");
    }
    if (kt+1 < NT){
      __builtin_amdgcn_s_barrier();
      __builtin_amdgcn_sched_barrier(0);
    }
  }
#pragma unroll
  for (int nf=0;nf<4;nf++){
    int col = bn*256 + wc*64 + nf*16 + lr;
    float bv = (col < nbias) ? bias[col] : 0.f;
#pragma unroll
    for (int mf=0; mf<MF; mf++){
      int row0 = bm*BM + wr*WRB + mf*16 + lg*4;
#pragma unroll
      for (int r=0;r<4;r++){
        int row = row0 + r;
        float v = acc[mf][nf][r] + bv;
        if constexpr (EPI==0){
          outb[(size_t)row*N + col] = f2b(v);
        } else {
          int bb = row>>10;
          float g = ada[(size_t)bb*6144 + (size_t)adaChunk*1024 + col];
          outf[(size_t)row*1024 + col] = xres[(size_t)row*1024 + col] + g*v;
        }
      }
    }
  }
}

// ---------------- qkv repack: rms-norm q,k per head, fragment-major K/V for attention ----------------
__global__ __launch_bounds__(256) void repack_qkv(const u16* __restrict__ qkvO,
    const float* __restrict__ qnw, const float* __restrict__ knw,
    u16* __restrict__ qO, u16* __restrict__ kO, u16* __restrict__ vO)
{
  __shared__ u16 ldsv[64][64];
  int bh = blockIdx.y, b = bh>>4, h = bh&15;
  int n0 = blockIdx.x*64;
  int t = threadIdx.x;
  int nr = t>>2, qd = (t&3)*16;
  const u16* rowp = qkvO + (size_t)(b*1024 + n0 + nr)*3072;
  // Q: rms-norm * qn_w * (1/8)*log2e
  {
    u16x8 a0 = *(const u16x8*)(rowp + h*64 + qd);
    u16x8 a1 = *(const u16x8*)(rowp + h*64 + qd + 8);
    float f[16]; float ss=0;
#pragma unroll
    for (int jj=0;jj<8;jj++){ f[jj]=b2f(a0[jj]); f[8+jj]=b2f(a1[jj]); }
#pragma unroll
    for (int jj=0;jj<16;jj++) ss += f[jj]*f[jj];
    ss += __shfl_xor(ss,1); ss += __shfl_xor(ss,2);
    float rinv = rsqrtf(ss*(1.f/64.f)+1e-6f)*0.125f*1.44269504089f;
    u16x8 o0,o1;
#pragma unroll
    for (int jj=0;jj<8;jj++){ o0[jj]=f2b(f[jj]*rinv*qnw[qd+jj]); o1[jj]=f2b(f[8+jj]*rinv*qnw[qd+8+jj]); }
    u16* dst = qO + ((size_t)bh*1024 + n0 + nr)*64 + qd;
    *(u16x8*)dst = o0; *(u16x8*)(dst+8) = o1;
  }
  // K: rms-norm * kn_w -> fragment-major
  {
    u16x8 a0 = *(const u16x8*)(rowp + 1024 + h*64 + qd);
    u16x8 a1 = *(const u16x8*)(rowp + 1024 + h*64 + qd + 8);
    float f[16]; float ss=0;
#pragma unroll
    for (int jj=0;jj<8;jj++){ f[jj]=b2f(a0[jj]); f[8+jj]=b2f(a1[jj]); }
#pragma unroll
    for (int jj=0;jj<16;jj++) ss += f[jj]*f[jj];
    ss += __shfl_xor(ss,1); ss += __shfl_xor(ss,2);
    float rinv = rsqrtf(ss*(1.f/64.f)+1e-6f);
    u16x8 o0,o1;
#pragma unroll
    for (int jj=0;jj<8;jj++){ o0[jj]=f2b(f[jj]*rinv*knw[qd+jj]); o1[jj]=f2b(f[8+jj]*rinv*knw[qd+8+jj]); }
    int t16 = (n0 + nr)>>4, lrk = nr&15;
    {
      int d0 = qd, c = d0>>5, lg = (d0>>3)&3;
      *(u16x8*)(kO + (size_t)bh*65536 + ((size_t)(t16*2+c)*64 + lg*16 + lrk)*8) = o0;
    }
    {
      int d0 = qd+8, c = d0>>5, lg = (d0>>3)&3;
      *(u16x8*)(kO + (size_t)bh*65536 + ((size_t)(t16*2+c)*64 + lg*16 + lrk)*8) = o1;
    }
  }
  // V: transpose via LDS, then write fragment-major
  {
    u16x8 a0 = *(const u16x8*)(rowp + 2048 + h*64 + qd);
    u16x8 a1 = *(const u16x8*)(rowp + 2048 + h*64 + qd + 8);
#pragma unroll
    for (int jj=0;jj<8;jj++){ ldsv[qd+jj][nr] = a0[jj]; ldsv[qd+8+jj][nr] = a1[jj]; }
  }
  __syncthreads();
  {
    int d = t>>2, ns = (t&3)*16;
    int tt = d>>4, lrv = d&15;
    int m = (n0 + ns)>>5;
    int hf = (ns>>4)&1;
    u16* basep = vO + (size_t)bh*65536 + ((size_t)(m*4+tt)*64 + lrv)*8 + hf*4;
#pragma unroll
    for (int g=0; g<4; ++g){
      u16x4 wv4 = { ldsv[d][ns+g*4], ldsv[d][ns+g*4+1], ldsv[d][ns+g*4+2], ldsv[d][ns+g*4+3] };
      *(u16x4*)(basep + (size_t)g*128) = wv4;
    }
  }
}

// ---------------- flash attention: split-K x2, coalesced fragment loads, defer-max, exp2 ----------------
__global__ __launch_bounds__(512) void attn_fwd(const u16* __restrict__ qO,
    const u16* __restrict__ kO, const u16* __restrict__ vO, u16* __restrict__ o)
{
  __shared__ __align__(16) float obuf[4][64][16];
  __shared__ __align__(16) float mlb[4][2][2][16];
  int bh = blockIdx.y, b = bh>>4, h = bh&15;
  int w = threadIdx.x>>6, lane = threadIdx.x&63;
  int pair = w>>1, half = w&1;
  int lr = lane&15, lg = lane>>4;
  int q0 = blockIdx.x*64 + pair*16;
  const u16* qp = qO + ((size_t)bh*1024 + q0 + lr)*64 + lg*8;
  bf16x8 qf0 = *(const bf16x8*)qp;
  bf16x8 qf1 = *(const bf16x8*)(qp + 32);
  const u16* kb = kO + (size_t)bh*65536 + (size_t)half*32768 + (size_t)lane*8;
  const u16* vb = vO + (size_t)bh*65536 + (size_t)half*32768 + (size_t)lane*8;
  f32x4 oacc[4] = {};
  float mrun = -3.0e38f, lrun = 0.f;
  for (int it=0; it<16; ++it){
    const u16* kp = kb + (size_t)it*4096;
    bf16x8 k00 = *(const bf16x8*)(kp);
    bf16x8 k01 = *(const bf16x8*)(kp + 512);
    bf16x8 k10 = *(const bf16x8*)(kp + 1024);
    bf16x8 k11 = *(const bf16x8*)(kp + 1536);
    f32x4 s0 = {}, s1 = {};
    s0 = mfma16(k00, qf0, s0); s0 = mfma16(k01, qf1, s0);
    s1 = mfma16(k10, qf0, s1); s1 = mfma16(k11, qf1, s1);
    const u16* vp = vb + (size_t)it*2048;
    bf16x8 vv[4];
#pragma unroll
    for (int tt=0;tt<4;tt++) vv[tt] = *(const bf16x8*)(vp + tt*512);
    float pm = fmaxf(fmaxf(fmaxf(s0[0],s0[1]),fmaxf(s0[2],s0[3])),
                     fmaxf(fmaxf(s1[0],s1[1]),fmaxf(s1[2],s1[3])));
    pm = fmaxf(pm, __shfl_xor(pm, 16));
    pm = fmaxf(pm, __shfl_xor(pm, 32));
    if (__any(pm > mrun + 8.f)){
      float mnew = fmaxf(mrun, pm);
      float alpha = fexp2(mrun - mnew);
      mrun = mnew;
      lrun *= alpha;
      float ar[4];
#pragma unroll
      for (int r=0;r<4;r++) ar[r] = __shfl(alpha, lg*4 + r);
#pragma unroll
      for (int tt=0;tt<4;tt++)
#pragma unroll
        for (int r=0;r<4;r++) oacc[tt][r] *= ar[r];
    }
    float p0[4], p1[4]; float ls = 0.f;
#pragma unroll
    for (int r=0;r<4;r++){ p0[r]=fexp2(s0[r]-mrun); p1[r]=fexp2(s1[r]-mrun); ls += p0[r]+p1[r]; }
    ls += __shfl_xor(ls, 16); ls += __shfl_xor(ls, 32);
    lrun += ls;
    bf16x4 pa0, pa1;
#pragma unroll
    for (int r=0;r<4;r++){ pa0[r] = (__bf16)p0[r]; pa1[r] = (__bf16)p1[r]; }
#pragma unroll
    for (int tt=0;tt<4;tt++){
      bf16x4* vh = (bf16x4*)&vv[tt];
      oacc[tt] = mfma16k16(pa0, vh[0], oacc[tt]);
      oacc[tt] = mfma16k16(pa1, vh[1], oacc[tt]);
    }
  }
  if (lg==0){ mlb[pair][half][0][lr] = mrun; mlb[pair][half][1][lr] = lrun; }
  __syncthreads();
  f32x4 m0 = *(const f32x4*)&mlb[pair][0][0][lg*4];
  f32x4 l0 = *(const f32x4*)&mlb[pair][0][1][lg*4];
  f32x4 m1 = *(const f32x4*)&mlb[pair][1][0][lg*4];
  f32x4 l1 = *(const f32x4*)&mlb[pair][1][1][lg*4];
  f32x4 fh;
#pragma unroll
  for (int r=0;r<4;r++){
    float m = fmaxf(m0[r], m1[r]);
    float e0 = fexp2(m0[r]-m), e1 = fexp2(m1[r]-m);
    float li = 1.f/(l0[r]*e0 + l1[r]*e1);
    fh[r] = (half ? e1 : e0)*li;
  }
  if (half==1){
#pragma unroll
    for (int tt=0;tt<4;tt++){
      f32x4 tv;
#pragma unroll
      for (int r=0;r<4;r++) tv[r] = oacc[tt][r]*fh[r];
      *(f32x4*)&obuf[pair][lane][tt*4] = tv;
    }
  }
  __syncthreads();
  if (half==0){
#pragma unroll
    for (int tt=0;tt<4;tt++){
      f32x4 p = *(const f32x4*)&obuf[pair][lane][tt*4];
#pragma unroll
      for (int r=0;r<4;r++){
        int row = (b<<10) + q0 + lg*4 + r;
        int col = h*64 + tt*16 + lr;
        o[(size_t)row*1024 + col] = f2b(oacc[tt][r]*fh[r] + p[r]);
      }
    }
  }
}

// ---------------- SwiGLU: hid = silu(x1)*x2, zero-padded to 2752 cols ----------------
__global__ __launch_bounds__(256) void swiglu_k(const u16* __restrict__ x12, u16* __restrict__ hid)
{
  int r = blockIdx.y;
  int c4 = blockIdx.x*256 + threadIdx.x;
  if (c4 >= 688) return;
  int cc = c4*4;
  const u16* rowp = x12 + (size_t)r*5632;
  u16x4 x1 = *(const u16x4*)(rowp + cc);
  u16x2 x2a = *(const u16x2*)(rowp + 2730 + cc);
  u16x2 x2b = *(const u16x2*)(rowp + 2730 + cc + 2);
  u16 x2v[4] = {x2a[0],x2a[1],x2b[0],x2b[1]};
  u16x4 o;
#pragma unroll
  for (int jj=0;jj<4;jj++){
    float a = b2f(x1[jj]);
    float g = silu_f(a)*b2f(x2v[jj]);
    o[jj] = (cc+jj < 2730) ? f2b(g) : (u16)0;
  }
  *(u16x4*)&hid[(size_t)r*2752 + cc] = o;
}

extern "C" void kernel_launch(void* const* d_in, const int* in_sizes, int n_in,
                              void* d_out, int out_size, void* d_ws, size_t ws_size,
                              hipStream_t stream)
{
  (void)in_sizes; (void)n_in; (void)out_size; (void)ws_size;
  const float* x    = (const float*)d_in[0];
  const float* c    = (const float*)d_in[1];
  const float* n1w  = (const float*)d_in[2];
  const float* cw   = (const float*)d_in[3];
  const float* cb   = (const float*)d_in[4];
  const float* qkvw = (const float*)d_in[5];
  const float* qkvb = (const float*)d_in[6];
  const float* qnw  = (const float*)d_in[7];
  const float* knw  = (const float*)d_in[8];
  const float* pw   = (const float*)d_in[9];
  const float* pb   = (const float*)d_in[10];
  const float* ew   = (const float*)d_in[11];
  const float* eb   = (const float*)d_in[12];
  const float* n2w  = (const float*)d_in[13];
  const float* w12w = (const float*)d_in[14];
  const float* w12b = (const float*)d_in[15];
  const float* w3w  = (const float*)d_in[16];
  const float* w3b  = (const float*)d_in[17];
  const float* adaw = (const float*)d_in[18];
  const float* adab = (const float*)d_in[19];
  float* out = (float*)d_out;
  char* ws = (char*)d_ws;
  auto U = [&](size_t off){ return (u16*)(ws + off); };
  auto F = [&](size_t off){ return (float*)(ws + off); };

  // weight conversions (bf16, zero-padded)
  convert_pad<<<dim3(1,1024), 256, 0, stream>>>(cw,   U(OFF_WC),   1024, 1024, 1024);
  convert_pad<<<dim3(1,3072), 256, 0, stream>>>(qkvw, U(OFF_WQKV), 3072, 1024, 1024);
  convert_pad<<<dim3(1,1024), 256, 0, stream>>>(pw,   U(OFF_WPROJ),1024, 1024, 1024);
  convert_pad<<<dim3(1,1024), 256, 0, stream>>>(ew,   U(OFF_WEXP), 1024, 1024, 1024);
  convert_pad<<<dim3(1,5632), 256, 0, stream>>>(w12w, U(OFF_WW12), 5460, 1024, 1024);
  convert_pad<<<dim3(3,1024), 256, 0, stream>>>(w3w,  U(OFF_WW3),  1024, 2730, 2752);

  ada_kernel<<<1536, 256, 0, stream>>>(c, adaw, adab, F(OFF_ADA));

  // attention branch
  rms_mod<<<4096, 256, 0, stream>>>(x, n1w, F(OFF_ADA), 0, U(OFF_H1));
  gemm_bt<0><<<dim3(8,32),  256, 0, stream>>>(U(OFF_H1), U(OFF_WC),   cb,   1024, 1024, 1024, U(OFF_HC),   nullptr, nullptr, 0, nullptr);
  gemm_dp<256,0><<<dim3(12,16), 512, 0, stream>>>(U(OFF_HC), U(OFF_WQKV), qkvb, 3072, 1024, 3072, U(OFF_QKVO), nullptr, nullptr, 0, nullptr);
  repack_qkv<<<dim3(16,64), 256, 0, stream>>>(U(OFF_QKVO), qnw, knw, U(OFF_Q), U(OFF_K), U(OFF_VT));
  attn_fwd<<<dim3(16,64), 512, 0, stream>>>(U(OFF_Q), U(OFF_K), U(OFF_VT), U(OFF_O));
  gemm_bt<0><<<dim3(8,32), 256, 0, stream>>>(U(OFF_O),  U(OFF_WPROJ), pb, 1024, 1024, 1024, U(OFF_PR), nullptr, nullptr, 0, nullptr);
  gemm_bt<1><<<dim3(8,32), 256, 0, stream>>>(U(OFF_PR), U(OFF_WEXP),  eb, 1024, 1024, 1024, nullptr, x, F(OFF_ADA), 2, F(OFF_X2));

  // FFN branch
  rms_mod<<<4096, 256, 0, stream>>>(F(OFF_X2), n2w, F(OFF_ADA), 3, U(OFF_H2));
  gemm_dp<128,0><<<dim3(22,32), 512, 0, stream>>>(U(OFF_H2), U(OFF_WW12), w12b, 5632, 1024, 5460, U(OFF_X12), nullptr, nullptr, 0, nullptr);
  swiglu_k<<<dim3(3,4096), 256, 0, stream>>>(U(OFF_X12), U(OFF_HID));
  gemm_dp<128,1><<<dim3(4,32), 512, 0, stream>>>(U(OFF_HID), U(OFF_WW3), w3b, 1024, 2752, 1024, nullptr, F(OFF_X2), F(OFF_ADA), 5, out);
}